// Round 4
// baseline (1465.362 us; speedup 1.0000x reference)
//
#include <hip/hip_runtime.h>
#include <math.h>

typedef unsigned short u16;
typedef short short8 __attribute__((ext_vector_type(8)));
typedef float f32x4 __attribute__((ext_vector_type(4)));

#define LN_EPS 1e-5f

__device__ __forceinline__ float gelu_exact(float x){
    return 0.5f * x * (1.0f + erff(x * 0.70710678118654752f));
}
__device__ __forceinline__ float sigmoidf_(float x){
    return 1.0f / (1.0f + __expf(-x));
}
__device__ __forceinline__ u16 f2bf(float f){            // RTNE f32->bf16
    unsigned u = __float_as_uint(f);
    u += 0x7fffu + ((u >> 16) & 1u);
    return (u16)(u >> 16);
}
__device__ __forceinline__ float b2f(u16 u){
    return __uint_as_float(((unsigned)u) << 16);
}

#define GLLDS(gp, lp) __builtin_amdgcn_global_load_lds( \
    (const __attribute__((address_space(1))) unsigned int*)(const void*)(gp), \
    (__attribute__((address_space(3))) unsigned int*)(void*)(lp), 16, 0, 0)

// ---------------------------------------------------------------------------
// a_adp = softmax(relu(emb_src @ emb_dst^T)) -> bf16 [1024][1024]
// ---------------------------------------------------------------------------
__global__ __launch_bounds__(256) void k_adp(const float* __restrict__ es,
                                             const float* __restrict__ ed,
                                             u16* __restrict__ aadp){
    __shared__ float srow[1024];
    __shared__ float s_es[16];
    __shared__ float sredm[4];
    __shared__ float sreds[4];
    const int n   = blockIdx.x;
    const int tid = threadIdx.x;
    const int wid = tid >> 6, lane = tid & 63;
    if (tid < 16) s_es[tid] = es[n*16 + tid];
    __syncthreads();
    float lmax = 0.0f;
    for (int m = tid; m < 1024; m += 256){
        const float* edm = ed + m*16;
        float z = 0.f;
        #pragma unroll
        for (int r = 0; r < 16; r++) z = fmaf(s_es[r], edm[r], z);
        z = fmaxf(z, 0.0f);
        srow[m] = z;
        lmax = fmaxf(lmax, z);
    }
    #pragma unroll
    for (int o = 32; o > 0; o >>= 1) lmax = fmaxf(lmax, __shfl_xor(lmax, o, 64));
    if (lane == 0) sredm[wid] = lmax;
    __syncthreads();
    const float tmax = fmaxf(fmaxf(sredm[0], sredm[1]), fmaxf(sredm[2], sredm[3]));
    float lsum = 0.f;
    for (int m = tid; m < 1024; m += 256){
        float e = expf(srow[m] - tmax);
        srow[m] = e;
        lsum += e;
    }
    #pragma unroll
    for (int o = 32; o > 0; o >>= 1) lsum += __shfl_xor(lsum, o, 64);
    if (lane == 0) sreds[wid] = lsum;
    __syncthreads();
    const float inv = 1.0f / (sreds[0] + sreds[1] + sreds[2] + sreds[3]);
    for (int m = tid; m < 1024; m += 256) aadp[(size_t)n*1024 + m] = f2bf(srow[m] * inv);
}

// ---------------------------------------------------------------------------
__global__ __launch_bounds__(256) void k_cvt(const float* __restrict__ in,
                                             u16* __restrict__ out){
    const int i = blockIdx.x*256 + threadIdx.x;
    const float4 v = ((const float4*)in)[i];
    ushort4 o;
    o.x = f2bf(v.x); o.y = f2bf(v.y); o.z = f2bf(v.z); o.w = f2bf(v.w);
    ((ushort4*)out)[i] = o;
}

__global__ __launch_bounds__(256) void k_bwd(const float* __restrict__ a,
                                             u16* __restrict__ at){
    __shared__ float t[32][33];
    const int bx = blockIdx.x*32, by = blockIdx.y*32;
    const int tx = threadIdx.x & 31, ty = threadIdx.x >> 5;
    #pragma unroll
    for (int i = 0; i < 4; i++)
        t[ty + 8*i][tx] = a[(size_t)(by + ty + 8*i)*1024 + bx + tx];
    __syncthreads();
    #pragma unroll
    for (int i = 0; i < 4; i++)
        at[(size_t)(bx + ty + 8*i)*1024 + by + tx] = f2bf(t[tx][ty + 8*i]);
}

// ---------------------------------------------------------------------------
// MFMA gating kernel (coalesced stores version).
// ---------------------------------------------------------------------------
__global__ __launch_bounds__(256, 2) void k_gating(
    const float* __restrict__ x,    const float* __restrict__ ctx,
    const float* __restrict__ Wg1,  const float* __restrict__ bg1,
    const float* __restrict__ Wg2,  const float* __restrict__ bg2,
    const float* __restrict__ Ws1,  const float* __restrict__ bs1,
    const float* __restrict__ Ws2,  const float* __restrict__ bs2,
    const float* __restrict__ Wsrc, const float* __restrict__ bsrc,
    const float* __restrict__ Wdst, const float* __restrict__ bdst,
    const float* __restrict__ Wself,const float* __restrict__ bself,
    float* __restrict__ gates, u16* __restrict__ scaleb,
    float* __restrict__ acc,
    u16* __restrict__ xTp, u16* __restrict__ xTd, u16* __restrict__ xTs)
{
    __shared__ u16 H1[16384];      // 32 KB
    __shared__ u16 H2[16384];      // 32 KB
    __shared__ float sgate[256], dgate[256];

    const int tid  = threadIdx.x;
    const int wv   = tid >> 6, lane = tid & 63;
    const int lr   = lane & 15, lg = lane >> 4;
    const int wtok = wv * 64;
    const int tokbase = blockIdx.x * 256;
    const int bt = blockIdx.x >> 2;
    const int n0 = (blockIdx.x & 3) * 256;

    auto stage_coop = [&](u16* H, const float* g){
        #pragma unroll
        for (int i = 0; i < 16; i++){
            const int fid = i*256 + tid;
            const int t = fid >> 4, q = fid & 15;
            const float4 v = *(const float4*)&g[(size_t)t*64 + q*4];
            ushort4 s;
            s.x = f2bf(v.x); s.y = f2bf(v.y); s.z = f2bf(v.z); s.w = f2bf(v.w);
            *(ushort4*)&H[t*64 + ((((q>>1) ^ (t & 7)) << 3) | ((q & 1)*4))] = s;
        }
    };
    auto afrag = [&](const u16* H, int row, int kb)->short8{
        return *(const short8*)&H[wv*4096 + row*64 + ((kb ^ (row & 7)) << 3)];
    };
    auto wfrag = [&](const float* W, int o, int kb8)->short8{
        const float4 a = *(const float4*)&W[o*64 + kb8];
        const float4 b = *(const float4*)&W[o*64 + kb8 + 4];
        short8 s;
        s[0]=f2bf(a.x); s[1]=f2bf(a.y); s[2]=f2bf(a.z); s[3]=f2bf(a.w);
        s[4]=f2bf(b.x); s[5]=f2bf(b.y); s[6]=f2bf(b.z); s[7]=f2bf(b.w);
        return s;
    };
    auto gemm64 = [&](const u16* Hs, const float* W, const float* bias, f32x4 (&c)[4][4]){
        #pragma unroll
        for (int n = 0; n < 4; n++){
            const float bv = bias[n*16 + lr];
            #pragma unroll
            for (int m = 0; m < 4; m++){ f32x4 t = {bv,bv,bv,bv}; c[m][n] = t; }
        }
        #pragma unroll
        for (int kk = 0; kk < 2; kk++){
            short8 a[4];
            #pragma unroll
            for (int m = 0; m < 4; m++) a[m] = afrag(Hs, m*16 + lr, kk*4 + lg);
            #pragma unroll
            for (int n = 0; n < 4; n++){
                const short8 w = wfrag(W, n*16 + lr, kk*32 + lg*8);
                #pragma unroll
                for (int m = 0; m < 4; m++)
                    c[m][n] = __builtin_amdgcn_mfma_f32_16x16x32_bf16(a[m], w, c[m][n], 0,0,0);
            }
        }
    };
    auto storeH = [&](u16* Hd, f32x4 (&c)[4][4]){
        #pragma unroll
        for (int m = 0; m < 4; m++)
            #pragma unroll
            for (int n = 0; n < 4; n++){
                const int f = n*16 + lr;
                #pragma unroll
                for (int r = 0; r < 4; r++){
                    const int t = m*16 + lg*4 + r;
                    Hd[wv*4096 + t*64 + ((((f>>3) ^ (t & 7)) << 3) | (f & 7))] = f2bf(c[m][n][r]);
                }
            }
    };

    stage_coop(H1, ctx + (size_t)tokbase*64);
    __syncthreads();

    f32x4 c[4][4];

    // hg = gelu(ctx @ Wg1^T + bg1) -> H2
    gemm64(H1, Wg1, bg1, c);
    #pragma unroll
    for (int m = 0; m < 4; m++)
        #pragma unroll
        for (int n = 0; n < 4; n++)
            #pragma unroll
            for (int r = 0; r < 4; r++) c[m][n][r] = gelu_exact(c[m][n][r]);
    storeH(H2, c);

    // src/dst gates
    {
        f32x4 c2[4];
        const float bv = (lr == 0) ? bsrc[0] : (lr == 1 ? bdst[0] : 0.f);
        #pragma unroll
        for (int m = 0; m < 4; m++){ f32x4 t = {bv,bv,bv,bv}; c2[m] = t; }
        #pragma unroll
        for (int kk = 0; kk < 2; kk++){
            short8 a[4];
            #pragma unroll
            for (int m = 0; m < 4; m++) a[m] = afrag(H1, m*16 + lr, kk*4 + lg);
            short8 w = {0,0,0,0,0,0,0,0};
            if (lr == 0) w = wfrag(Wsrc, 0, kk*32 + lg*8);
            else if (lr == 1) w = wfrag(Wdst, 0, kk*32 + lg*8);
            #pragma unroll
            for (int m = 0; m < 4; m++)
                c2[m] = __builtin_amdgcn_mfma_f32_16x16x32_bf16(a[m], w, c2[m], 0,0,0);
        }
        #pragma unroll
        for (int m = 0; m < 4; m++)
            #pragma unroll
            for (int r = 0; r < 4; r++){
                const int t = wtok + m*16 + lg*4 + r;
                const float v = sigmoidf_(c2[m][r]);
                if (lr == 0) sgate[t] = v;
                if (lr == 1) dgate[t] = v;
            }
    }

    // hs = gelu(ctx @ Ws1^T + bs1) -> H1
    gemm64(H1, Ws1, bs1, c);
    #pragma unroll
    for (int m = 0; m < 4; m++)
        #pragma unroll
        for (int n = 0; n < 4; n++)
            #pragma unroll
            for (int r = 0; r < 4; r++) c[m][n][r] = gelu_exact(c[m][n][r]);
    storeH(H1, c);

    // gates = sigmoid(hg @ Wg2^T + bg2)
    float g0[4][4];
    {
        f32x4 c3[4];
        const float bv = (lr < 4) ? bg2[lr] : 0.f;
        #pragma unroll
        for (int m = 0; m < 4; m++){ f32x4 t = {bv,bv,bv,bv}; c3[m] = t; }
        #pragma unroll
        for (int kk = 0; kk < 2; kk++){
            short8 a[4];
            #pragma unroll
            for (int m = 0; m < 4; m++) a[m] = afrag(H2, m*16 + lr, kk*4 + lg);
            short8 w = {0,0,0,0,0,0,0,0};
            if (lr < 4) w = wfrag(Wg2, lr, kk*32 + lg*8);
            #pragma unroll
            for (int m = 0; m < 4; m++)
                c3[m] = __builtin_amdgcn_mfma_f32_16x16x32_bf16(a[m], w, c3[m], 0,0,0);
        }
        #pragma unroll
        for (int m = 0; m < 4; m++)
            #pragma unroll
            for (int r = 0; r < 4; r++){
                const float v = sigmoidf_(c3[m][r]);
                if (lr < 4)
                    gates[(size_t)(tokbase + wtok + m*16 + lg*4 + r)*4 + lr] = v;
                g0[m][r] = __shfl(v, lane & 48, 64);
            }
    }

    // scale = sigmoid(hs @ Ws2^T + bs2) -> H1 -> coalesced store (8 tokens/iter)
    gemm64(H1, Ws2, bs2, c);
    #pragma unroll
    for (int m = 0; m < 4; m++)
        #pragma unroll
        for (int n = 0; n < 4; n++)
            #pragma unroll
            for (int r = 0; r < 4; r++) c[m][n][r] = sigmoidf_(c[m][n][r]);
    storeH(H1, c);
    {
        #pragma unroll
        for (int it = 0; it < 8; it++){
            const int r2  = wtok + it*8 + (lane >> 3);   // block-local token
            const int sub = lane & 7;
            const short8 v = *(const short8*)&H1[r2*64 + ((sub ^ (r2 & 7)) << 3)];
            *(short8*)&scaleb[(size_t)(tokbase + r2)*64 + sub*8] = v;
        }
    }

    __syncthreads();
    stage_coop(H2, x + (size_t)tokbase*64);
    __syncthreads();

    // self = x @ Wself^T + bself; acc = g0 * self
    gemm64(H2, Wself, bself, c);
    #pragma unroll
    for (int m = 0; m < 4; m++)
        #pragma unroll
        for (int n = 0; n < 4; n++)
            #pragma unroll
            for (int r = 0; r < 4; r++)
                acc[(size_t)(tokbase + wtok + m*16 + lg*4 + r)*64 + n*16 + lr]
                    = g0[m][r] * c[m][n][r];

    // coalesced f-major transposed outputs: thread tid owns token-row tid
    {
        const float dg = dgate[tid], sg = sgate[tid];
        const size_t ob = (size_t)bt*65536 + n0 + tid;
        #pragma unroll
        for (int fb = 0; fb < 8; fb++){
            const short8 v = *(const short8*)&H2[tid*64 + ((fb ^ (tid & 7)) << 3)];
            #pragma unroll
            for (int j = 0; j < 8; j++){
                const u16 raw = (u16)v[j];
                const float xv = b2f(raw);
                const size_t o = ob + (size_t)(fb*8 + j)*1024;
                xTp[o] = raw;
                xTd[o] = f2bf(xv * dg);
                xTs[o] = f2bf(xv * sg);
            }
        }
    }
}

// ---------------------------------------------------------------------------
// Merged 3-branch diffusion step.  STEP1: sources xT*, writes tmp*, acc += E.
// STEP2: sources tmp*, fused final epilogue (scale, gelu, residual, LN) -> acc.
// ---------------------------------------------------------------------------
template<bool STEP1>
__global__ __launch_bounds__(256, 2) void k_diff3(
    const u16* __restrict__ adj0, const u16* __restrict__ adj1, const u16* __restrict__ adj2,
    const u16* __restrict__ src0, const u16* __restrict__ src1, const u16* __restrict__ src2,
    const float* __restrict__ W0, const float* __restrict__ B0,
    const float* __restrict__ W1, const float* __restrict__ B1,
    const float* __restrict__ W2, const float* __restrict__ B2,
    const float* __restrict__ gates,
    float* __restrict__ acc,
    u16* __restrict__ tmp0, u16* __restrict__ tmp1, u16* __restrict__ tmp2,
    const float* __restrict__ x, const u16* __restrict__ scaleb,
    const float* __restrict__ gamma, const float* __restrict__ beta)
{
    __shared__ u16 sA[2][256*64];   // 2 x 32 KB
    __shared__ u16 sB[2][64*64];    // 2 x 8 KB

    const int tid = threadIdx.x;
    const int bt  = blockIdx.y;
    const int n0  = blockIdx.x * 256;
    const int wv  = tid >> 6, lane = tid & 63;
    const int lr  = lane & 15, lg = lane >> 4;
    const int wrow0 = wv * 64;

    const f32x4 z4 = {0.f, 0.f, 0.f, 0.f};
    f32x4 E[4][4];
    #pragma unroll
    for (int m = 0; m < 4; m++)
        #pragma unroll
        for (int n = 0; n < 4; n++) E[m][n] = z4;

    for (int br = 0; br < 3; br++){
        const u16* adj  = (br==0) ? adj0 : (br==1) ? adj1 : adj2;
        const u16* srcT = (br==0) ? src0 : (br==1) ? src1 : src2;
        const float* W  = (br==0) ? W0 : (br==1) ? W1 : W2;
        const float* bias = (br==0) ? B0 : (br==1) ? B1 : B2;

        const u16* asrc = adj  + (size_t)n0 * 1024;
        const u16* bsrc = srcT + (size_t)bt * 65536;

        auto stage = [&](int buf, int kt){
            const int m0 = kt * 64;
            #pragma unroll
            for (int i = 0; i < 8; i++){
                const int s = i*256 + tid;
                const int row = s >> 3, kbp = s & 7;
                const int kb = kbp ^ (row & 7);
                GLLDS(asrc + (size_t)row*1024 + m0 + kb*8, &sA[buf][s*8]);
            }
            #pragma unroll
            for (int i = 0; i < 2; i++){
                const int s = i*256 + tid;
                const int row = s >> 3, kbp = s & 7;
                const int kb = kbp ^ (row & 7);
                GLLDS(bsrc + (size_t)row*1024 + m0 + kb*8, &sB[buf][s*8]);
            }
        };

        f32x4 c[4][4];
        #pragma unroll
        for (int m = 0; m < 4; m++)
            #pragma unroll
            for (int n = 0; n < 4; n++) c[m][n] = z4;

        stage(0, 0);
        asm volatile("s_waitcnt vmcnt(0)" ::: "memory");
        __syncthreads();

        int cur = 0;
        for (int kt = 0; kt < 16; kt++){
            if (kt < 15) stage(cur ^ 1, kt + 1);
            const u16* A = sA[cur];
            const u16* B = sB[cur];
            #pragma unroll
            for (int kk = 0; kk < 2; kk++){
                const int kb = lg + kk*4;
                const int sw = kb ^ (lr & 7);
                short8 a[4], b[4];
                #pragma unroll
                for (int m = 0; m < 4; m++)
                    a[m] = *(const short8*)&A[(wrow0 + m*16 + lr)*64 + (sw << 3)];
                #pragma unroll
                for (int n = 0; n < 4; n++)
                    b[n] = *(const short8*)&B[(n*16 + lr)*64 + (sw << 3)];
                #pragma unroll
                for (int m = 0; m < 4; m++)
                    #pragma unroll
                    for (int n = 0; n < 4; n++)
                        c[m][n] = __builtin_amdgcn_mfma_f32_16x16x32_bf16(
                            a[m], b[n], c[m][n], 0, 0, 0);
            }
            asm volatile("s_waitcnt vmcnt(0)" ::: "memory");
            __syncthreads();
            cur ^= 1;
        }

        // stash yT (bf16, swizzled) into sA[0]; W into sB[0]
        u16* yT = &sA[0][0];
        u16* sW = &sB[0][0];
        #pragma unroll
        for (int m = 0; m < 4; m++)
            #pragma unroll
            for (int n = 0; n < 4; n++){
                const int f = n*16 + lr;
                #pragma unroll
                for (int r = 0; r < 4; r++){
                    const int row = wrow0 + m*16 + lg*4 + r;
                    yT[row*64 + (((f >> 3) ^ (row & 7)) << 3) + (f & 7)] = f2bf(c[m][n][r]);
                }
            }
        for (int i = tid; i < 4096; i += 256){
            const int o = i >> 6, f = i & 63;
            sW[o*64 + (((f >> 3) ^ (o & 7)) << 3) + (f & 7)] = f2bf(W[i]);
        }
        __syncthreads();

        // coalesced tmp write: thread tid owns node-row tid
        if (STEP1){
            u16* tmp = (br==0) ? tmp0 : (br==1) ? tmp1 : tmp2;
            const size_t ob = (size_t)bt*65536 + n0 + tid;
            #pragma unroll
            for (int fb = 0; fb < 8; fb++){
                const short8 v = *(const short8*)&yT[tid*64 + ((fb ^ (tid & 7)) << 3)];
                #pragma unroll
                for (int j = 0; j < 8; j++)
                    tmp[ob + (size_t)(fb*8 + j)*1024] = (u16)v[j];
            }
        }

        // lin = y @ W^T (K=64)
        f32x4 lin[4][4];
        #pragma unroll
        for (int m = 0; m < 4; m++)
            #pragma unroll
            for (int n = 0; n < 4; n++) lin[m][n] = z4;
        #pragma unroll
        for (int kk = 0; kk < 2; kk++){
            const int kb = lg + kk*4;
            const int sw = kb ^ (lr & 7);
            short8 ya[4], wb[4];
            #pragma unroll
            for (int m = 0; m < 4; m++)
                ya[m] = *(const short8*)&yT[(wrow0 + m*16 + lr)*64 + (sw << 3)];
            #pragma unroll
            for (int n = 0; n < 4; n++)
                wb[n] = *(const short8*)&sW[(n*16 + lr)*64 + (sw << 3)];
            #pragma unroll
            for (int m = 0; m < 4; m++)
                #pragma unroll
                for (int n = 0; n < 4; n++)
                    lin[m][n] = __builtin_amdgcn_mfma_f32_16x16x32_bf16(
                        ya[m], wb[n], lin[m][n], 0, 0, 0);
        }

        // E += g_br * (lin + bias)
        #pragma unroll
        for (int m = 0; m < 4; m++){
            float g[4];
            #pragma unroll
            for (int r = 0; r < 4; r++){
                const int node = n0 + wrow0 + m*16 + lg*4 + r;
                g[r] = gates[((size_t)bt*1024 + node)*4 + (br + 1)];
            }
            #pragma unroll
            for (int n = 0; n < 4; n++){
                const float bv = bias[n*16 + lr];
                #pragma unroll
                for (int r = 0; r < 4; r++)
                    E[m][n][r] += g[r] * (lin[m][n][r] + bv);
            }
        }
        __syncthreads();   // sA/sB free for next branch
    }

    if (STEP1){
        #pragma unroll
        for (int m = 0; m < 4; m++)
            #pragma unroll
            for (int r = 0; r < 4; r++){
                const size_t tok = (size_t)bt*1024 + n0 + wrow0 + m*16 + lg*4 + r;
                #pragma unroll
                for (int n = 0; n < 4; n++)
                    acc[tok*64 + n*16 + lr] += E[m][n][r];
            }
    } else {
        // fused finalize: mixed=(acc+E)*scale; h=x+gelu(mixed); LN -> acc(out)
        #pragma unroll
        for (int m = 0; m < 4; m++){
            #pragma unroll
            for (int r = 0; r < 4; r++){
                const size_t tok = (size_t)bt*1024 + n0 + wrow0 + m*16 + lg*4 + r;
                float h[4];
                #pragma unroll
                for (int n = 0; n < 4; n++){
                    const int f = n*16 + lr;
                    const float a = acc[tok*64 + f] + E[m][n][r];
                    const float mixed = a * b2f(scaleb[tok*64 + f]);
                    h[n] = x[tok*64 + f] + gelu_exact(mixed);
                }
                float s = h[0] + h[1] + h[2] + h[3];
                #pragma unroll
                for (int o = 8; o > 0; o >>= 1) s += __shfl_xor(s, o, 64);
                const float mu = s * (1.0f/64.0f);
                float vs = 0.f;
                #pragma unroll
                for (int n = 0; n < 4; n++){ const float d = h[n] - mu; vs += d*d; }
                #pragma unroll
                for (int o = 8; o > 0; o >>= 1) vs += __shfl_xor(vs, o, 64);
                const float inv = rsqrtf(vs * (1.0f/64.0f) + LN_EPS);
                #pragma unroll
                for (int n = 0; n < 4; n++){
                    const int f = n*16 + lr;
                    acc[tok*64 + f] = (h[n] - mu) * inv * gamma[f] + beta[f];
                }
            }
        }
    }
}

// ---------------------------------------------------------------------------
extern "C" void kernel_launch(void* const* d_in, const int* in_sizes, int n_in,
                              void* d_out, int out_size, void* d_ws, size_t ws_size,
                              hipStream_t stream)
{
    const float* x      = (const float*)d_in[0];
    const float* a_fwd  = (const float*)d_in[1];
    const float* ctx    = (const float*)d_in[2];
    const float* W_self = (const float*)d_in[3];
    const float* b_self = (const float*)d_in[4];
    const float* W_fwd  = (const float*)d_in[5];
    const float* b_fwd  = (const float*)d_in[6];
    const float* W_bwd  = (const float*)d_in[7];
    const float* b_bwd  = (const float*)d_in[8];
    const float* W_adp  = (const float*)d_in[9];
    const float* b_adp  = (const float*)d_in[10];
    const float* Wg1    = (const float*)d_in[11];
    const float* bg1    = (const float*)d_in[12];
    const float* Wg2    = (const float*)d_in[13];
    const float* bg2    = (const float*)d_in[14];
    const float* Ws1    = (const float*)d_in[15];
    const float* bs1    = (const float*)d_in[16];
    const float* Ws2    = (const float*)d_in[17];
    const float* bs2    = (const float*)d_in[18];
    const float* W_src  = (const float*)d_in[19];
    const float* b_src  = (const float*)d_in[20];
    const float* W_dst  = (const float*)d_in[21];
    const float* b_dst  = (const float*)d_in[22];
    const float* emb_src= (const float*)d_in[23];
    const float* emb_dst= (const float*)d_in[24];
    const float* gamma  = (const float*)d_in[25];
    const float* beta   = (const float*)d_in[26];

    float* out = (float*)d_out;
    char*  w   = (char*)d_ws;
    const size_t MB48 = 50331648ull;
    u16* afwd_bf = (u16*)(w);
    u16* abwd_bf = (u16*)(w + 2097152ull);
    u16* aadp_bf = (u16*)(w + 4194304ull);
    u16* xTp     = (u16*)(w + 6291456ull);
    u16* xTd     = (u16*)(w + 6291456ull + 1*MB48);
    u16* xTs     = (u16*)(w + 6291456ull + 2*MB48);
    u16* tmpF    = (u16*)(w + 6291456ull + 3*MB48);
    u16* tmpB    = (u16*)(w + 6291456ull + 4*MB48);
    u16* tmpA    = (u16*)(w + 6291456ull + 5*MB48);
    u16* scaleb  = (u16*)(w + 6291456ull + 6*MB48);
    float* gates = (float*)(w + 6291456ull + 7*MB48);

    k_adp   <<<1024, 256, 0, stream>>>(emb_src, emb_dst, aadp_bf);
    k_cvt   <<<1024, 256, 0, stream>>>(a_fwd, afwd_bf);
    k_bwd   <<<dim3(32,32), 256, 0, stream>>>(a_fwd, abwd_bf);
    k_gating<<<1536, 256, 0, stream>>>(x, ctx, Wg1,bg1, Wg2,bg2, Ws1,bs1, Ws2,bs2,
                                       W_src,b_src, W_dst,b_dst, W_self,b_self,
                                       gates, scaleb, out, xTp, xTd, xTs);

    dim3 g(4, 384);
    k_diff3<true ><<<g,256,0,stream>>>(afwd_bf, abwd_bf, aadp_bf,
                                       xTd, xTs, xTp,
                                       W_fwd, b_fwd, W_bwd, b_bwd, W_adp, b_adp,
                                       gates, out, tmpF, tmpB, tmpA,
                                       nullptr, nullptr, nullptr, nullptr);
    k_diff3<false><<<g,256,0,stream>>>(afwd_bf, abwd_bf, aadp_bf,
                                       tmpF, tmpB, tmpA,
                                       W_fwd+4096, b_fwd+64, W_bwd+4096, b_bwd+64,
                                       W_adp+4096, b_adp+64,
                                       gates, out, nullptr, nullptr, nullptr,
                                       x, scaleb, gamma, beta);
}

// Round 5
// 1054.884 us; speedup vs baseline: 1.3891x; 1.3891x over previous
//
#include <hip/hip_runtime.h>
#include <math.h>

typedef unsigned short u16;
typedef short short8 __attribute__((ext_vector_type(8)));
typedef float f32x4 __attribute__((ext_vector_type(4)));

#define LN_EPS 1e-5f

__device__ __forceinline__ float gelu_exact(float x){
    return 0.5f * x * (1.0f + erff(x * 0.70710678118654752f));
}
__device__ __forceinline__ float sigmoidf_(float x){
    return 1.0f / (1.0f + __expf(-x));
}
__device__ __forceinline__ u16 f2bf(float f){            // RTNE f32->bf16
    unsigned u = __float_as_uint(f);
    u += 0x7fffu + ((u >> 16) & 1u);
    return (u16)(u >> 16);
}
__device__ __forceinline__ float b2f(u16 u){
    return __uint_as_float(((unsigned)u) << 16);
}

#define GLLDS(gp, lp) __builtin_amdgcn_global_load_lds( \
    (const __attribute__((address_space(1))) unsigned int*)(const void*)(gp), \
    (__attribute__((address_space(3))) unsigned int*)(void*)(lp), 16, 0, 0)

// ---------------------------------------------------------------------------
// a_adp = softmax(relu(emb_src @ emb_dst^T)) -> bf16 [1024][1024]
// ---------------------------------------------------------------------------
__global__ __launch_bounds__(256) void k_adp(const float* __restrict__ es,
                                             const float* __restrict__ ed,
                                             u16* __restrict__ aadp){
    __shared__ float srow[1024];
    __shared__ float s_es[16];
    __shared__ float sredm[4];
    __shared__ float sreds[4];
    const int n   = blockIdx.x;
    const int tid = threadIdx.x;
    const int wid = tid >> 6, lane = tid & 63;
    if (tid < 16) s_es[tid] = es[n*16 + tid];
    __syncthreads();
    float lmax = 0.0f;
    for (int m = tid; m < 1024; m += 256){
        const float* edm = ed + m*16;
        float z = 0.f;
        #pragma unroll
        for (int r = 0; r < 16; r++) z = fmaf(s_es[r], edm[r], z);
        z = fmaxf(z, 0.0f);
        srow[m] = z;
        lmax = fmaxf(lmax, z);
    }
    #pragma unroll
    for (int o = 32; o > 0; o >>= 1) lmax = fmaxf(lmax, __shfl_xor(lmax, o, 64));
    if (lane == 0) sredm[wid] = lmax;
    __syncthreads();
    const float tmax = fmaxf(fmaxf(sredm[0], sredm[1]), fmaxf(sredm[2], sredm[3]));
    float lsum = 0.f;
    for (int m = tid; m < 1024; m += 256){
        float e = expf(srow[m] - tmax);
        srow[m] = e;
        lsum += e;
    }
    #pragma unroll
    for (int o = 32; o > 0; o >>= 1) lsum += __shfl_xor(lsum, o, 64);
    if (lane == 0) sreds[wid] = lsum;
    __syncthreads();
    const float inv = 1.0f / (sreds[0] + sreds[1] + sreds[2] + sreds[3]);
    for (int m = tid; m < 1024; m += 256) aadp[(size_t)n*1024 + m] = f2bf(srow[m] * inv);
}

// ---------------------------------------------------------------------------
__global__ __launch_bounds__(256) void k_cvt(const float* __restrict__ in,
                                             u16* __restrict__ out){
    const int i = blockIdx.x*256 + threadIdx.x;
    const float4 v = ((const float4*)in)[i];
    ushort4 o;
    o.x = f2bf(v.x); o.y = f2bf(v.y); o.z = f2bf(v.z); o.w = f2bf(v.w);
    ((ushort4*)out)[i] = o;
}

__global__ __launch_bounds__(256) void k_bwd(const float* __restrict__ a,
                                             u16* __restrict__ at){
    __shared__ float t[32][33];
    const int bx = blockIdx.x*32, by = blockIdx.y*32;
    const int tx = threadIdx.x & 31, ty = threadIdx.x >> 5;
    #pragma unroll
    for (int i = 0; i < 4; i++)
        t[ty + 8*i][tx] = a[(size_t)(by + ty + 8*i)*1024 + bx + tx];
    __syncthreads();
    #pragma unroll
    for (int i = 0; i < 4; i++)
        at[(size_t)(bx + ty + 8*i)*1024 + by + tx] = f2bf(t[tx][ty + 8*i]);
}

// ---------------------------------------------------------------------------
// MFMA gating kernel (round-4 version, coalesced stores).
// ---------------------------------------------------------------------------
__global__ __launch_bounds__(256, 2) void k_gating(
    const float* __restrict__ x,    const float* __restrict__ ctx,
    const float* __restrict__ Wg1,  const float* __restrict__ bg1,
    const float* __restrict__ Wg2,  const float* __restrict__ bg2,
    const float* __restrict__ Ws1,  const float* __restrict__ bs1,
    const float* __restrict__ Ws2,  const float* __restrict__ bs2,
    const float* __restrict__ Wsrc, const float* __restrict__ bsrc,
    const float* __restrict__ Wdst, const float* __restrict__ bdst,
    const float* __restrict__ Wself,const float* __restrict__ bself,
    float* __restrict__ gates, u16* __restrict__ scaleb,
    float* __restrict__ acc,
    u16* __restrict__ xTp, u16* __restrict__ xTd, u16* __restrict__ xTs)
{
    __shared__ u16 H1[16384];      // 32 KB
    __shared__ u16 H2[16384];      // 32 KB
    __shared__ float sgate[256], dgate[256];

    const int tid  = threadIdx.x;
    const int wv   = tid >> 6, lane = tid & 63;
    const int lr   = lane & 15, lg = lane >> 4;
    const int wtok = wv * 64;
    const int tokbase = blockIdx.x * 256;
    const int bt = blockIdx.x >> 2;
    const int n0 = (blockIdx.x & 3) * 256;

    auto stage_coop = [&](u16* H, const float* g){
        #pragma unroll
        for (int i = 0; i < 16; i++){
            const int fid = i*256 + tid;
            const int t = fid >> 4, q = fid & 15;
            const float4 v = *(const float4*)&g[(size_t)t*64 + q*4];
            ushort4 s;
            s.x = f2bf(v.x); s.y = f2bf(v.y); s.z = f2bf(v.z); s.w = f2bf(v.w);
            *(ushort4*)&H[t*64 + ((((q>>1) ^ (t & 7)) << 3) | ((q & 1)*4))] = s;
        }
    };
    auto afrag = [&](const u16* H, int row, int kb)->short8{
        return *(const short8*)&H[wv*4096 + row*64 + ((kb ^ (row & 7)) << 3)];
    };
    auto wfrag = [&](const float* W, int o, int kb8)->short8{
        const float4 a = *(const float4*)&W[o*64 + kb8];
        const float4 b = *(const float4*)&W[o*64 + kb8 + 4];
        short8 s;
        s[0]=f2bf(a.x); s[1]=f2bf(a.y); s[2]=f2bf(a.z); s[3]=f2bf(a.w);
        s[4]=f2bf(b.x); s[5]=f2bf(b.y); s[6]=f2bf(b.z); s[7]=f2bf(b.w);
        return s;
    };
    auto gemm64 = [&](const u16* Hs, const float* W, const float* bias, f32x4 (&c)[4][4]){
        #pragma unroll
        for (int n = 0; n < 4; n++){
            const float bv = bias[n*16 + lr];
            #pragma unroll
            for (int m = 0; m < 4; m++){ f32x4 t = {bv,bv,bv,bv}; c[m][n] = t; }
        }
        #pragma unroll
        for (int kk = 0; kk < 2; kk++){
            short8 a[4];
            #pragma unroll
            for (int m = 0; m < 4; m++) a[m] = afrag(Hs, m*16 + lr, kk*4 + lg);
            #pragma unroll
            for (int n = 0; n < 4; n++){
                const short8 w = wfrag(W, n*16 + lr, kk*32 + lg*8);
                #pragma unroll
                for (int m = 0; m < 4; m++)
                    c[m][n] = __builtin_amdgcn_mfma_f32_16x16x32_bf16(a[m], w, c[m][n], 0,0,0);
            }
        }
    };
    auto storeH = [&](u16* Hd, f32x4 (&c)[4][4]){
        #pragma unroll
        for (int m = 0; m < 4; m++)
            #pragma unroll
            for (int n = 0; n < 4; n++){
                const int f = n*16 + lr;
                #pragma unroll
                for (int r = 0; r < 4; r++){
                    const int t = m*16 + lg*4 + r;
                    Hd[wv*4096 + t*64 + ((((f>>3) ^ (t & 7)) << 3) | (f & 7))] = f2bf(c[m][n][r]);
                }
            }
    };

    stage_coop(H1, ctx + (size_t)tokbase*64);
    __syncthreads();

    f32x4 c[4][4];

    // hg = gelu(ctx @ Wg1^T + bg1) -> H2
    gemm64(H1, Wg1, bg1, c);
    #pragma unroll
    for (int m = 0; m < 4; m++)
        #pragma unroll
        for (int n = 0; n < 4; n++)
            #pragma unroll
            for (int r = 0; r < 4; r++) c[m][n][r] = gelu_exact(c[m][n][r]);
    storeH(H2, c);

    // src/dst gates
    {
        f32x4 c2[4];
        const float bv = (lr == 0) ? bsrc[0] : (lr == 1 ? bdst[0] : 0.f);
        #pragma unroll
        for (int m = 0; m < 4; m++){ f32x4 t = {bv,bv,bv,bv}; c2[m] = t; }
        #pragma unroll
        for (int kk = 0; kk < 2; kk++){
            short8 a[4];
            #pragma unroll
            for (int m = 0; m < 4; m++) a[m] = afrag(H1, m*16 + lr, kk*4 + lg);
            short8 w = {0,0,0,0,0,0,0,0};
            if (lr == 0) w = wfrag(Wsrc, 0, kk*32 + lg*8);
            else if (lr == 1) w = wfrag(Wdst, 0, kk*32 + lg*8);
            #pragma unroll
            for (int m = 0; m < 4; m++)
                c2[m] = __builtin_amdgcn_mfma_f32_16x16x32_bf16(a[m], w, c2[m], 0,0,0);
        }
        #pragma unroll
        for (int m = 0; m < 4; m++)
            #pragma unroll
            for (int r = 0; r < 4; r++){
                const int t = wtok + m*16 + lg*4 + r;
                const float v = sigmoidf_(c2[m][r]);
                if (lr == 0) sgate[t] = v;
                if (lr == 1) dgate[t] = v;
            }
    }

    // hs = gelu(ctx @ Ws1^T + bs1) -> H1
    gemm64(H1, Ws1, bs1, c);
    #pragma unroll
    for (int m = 0; m < 4; m++)
        #pragma unroll
        for (int n = 0; n < 4; n++)
            #pragma unroll
            for (int r = 0; r < 4; r++) c[m][n][r] = gelu_exact(c[m][n][r]);
    storeH(H1, c);

    // gates = sigmoid(hg @ Wg2^T + bg2)
    float g0[4][4];
    {
        f32x4 c3[4];
        const float bv = (lr < 4) ? bg2[lr] : 0.f;
        #pragma unroll
        for (int m = 0; m < 4; m++){ f32x4 t = {bv,bv,bv,bv}; c3[m] = t; }
        #pragma unroll
        for (int kk = 0; kk < 2; kk++){
            short8 a[4];
            #pragma unroll
            for (int m = 0; m < 4; m++) a[m] = afrag(H2, m*16 + lr, kk*4 + lg);
            short8 w = {0,0,0,0,0,0,0,0};
            if (lr < 4) w = wfrag(Wg2, lr, kk*32 + lg*8);
            #pragma unroll
            for (int m = 0; m < 4; m++)
                c3[m] = __builtin_amdgcn_mfma_f32_16x16x32_bf16(a[m], w, c3[m], 0,0,0);
        }
        #pragma unroll
        for (int m = 0; m < 4; m++)
            #pragma unroll
            for (int r = 0; r < 4; r++){
                const float v = sigmoidf_(c3[m][r]);
                if (lr < 4)
                    gates[(size_t)(tokbase + wtok + m*16 + lg*4 + r)*4 + lr] = v;
                g0[m][r] = __shfl(v, lane & 48, 64);
            }
    }

    // scale = sigmoid(hs @ Ws2^T + bs2) -> H1 -> coalesced store
    gemm64(H1, Ws2, bs2, c);
    #pragma unroll
    for (int m = 0; m < 4; m++)
        #pragma unroll
        for (int n = 0; n < 4; n++)
            #pragma unroll
            for (int r = 0; r < 4; r++) c[m][n][r] = sigmoidf_(c[m][n][r]);
    storeH(H1, c);
    {
        #pragma unroll
        for (int it = 0; it < 8; it++){
            const int r2  = wtok + it*8 + (lane >> 3);
            const int sub = lane & 7;
            const short8 v = *(const short8*)&H1[r2*64 + ((sub ^ (r2 & 7)) << 3)];
            *(short8*)&scaleb[(size_t)(tokbase + r2)*64 + sub*8] = v;
        }
    }

    __syncthreads();
    stage_coop(H2, x + (size_t)tokbase*64);
    __syncthreads();

    // self = x @ Wself^T + bself; acc = g0 * self
    gemm64(H2, Wself, bself, c);
    #pragma unroll
    for (int m = 0; m < 4; m++)
        #pragma unroll
        for (int n = 0; n < 4; n++)
            #pragma unroll
            for (int r = 0; r < 4; r++)
                acc[(size_t)(tokbase + wtok + m*16 + lg*4 + r)*64 + n*16 + lr]
                    = g0[m][r] * c[m][n][r];

    // coalesced f-major transposed outputs: thread tid owns token-row tid
    {
        const float dg = dgate[tid], sg = sgate[tid];
        const size_t ob = (size_t)bt*65536 + n0 + tid;
        #pragma unroll
        for (int fb = 0; fb < 8; fb++){
            const short8 v = *(const short8*)&H2[tid*64 + ((fb ^ (tid & 7)) << 3)];
            #pragma unroll
            for (int j = 0; j < 8; j++){
                const u16 raw = (u16)v[j];
                const float xv = b2f(raw);
                const size_t o = ob + (size_t)(fb*8 + j)*1024;
                xTp[o] = raw;
                xTd[o] = f2bf(xv * dg);
                xTs[o] = f2bf(xv * sg);
            }
        }
    }
}

// ---------------------------------------------------------------------------
// MFMA diffusion GEMM + fused linear/gate epilogue (round-3 structure).
// Changes vs round 3:
//  - 1-D grid of 1536 with XCD-aware remap: each XCD owns a contiguous bt
//    range; the 4 n-tile blocks of one bt are adjacent on the same XCD, so
//    srcT[bt] is HBM-fetched once per XCD and L2-hit by siblings.
//  - tmp write is coalesced (per-node stores from the swizzled yT LDS stash).
// ---------------------------------------------------------------------------
template<bool WRITE_TMP>
__global__ __launch_bounds__(256, 2) void k_diffmm(
    const u16* __restrict__ adj,  const u16* __restrict__ srcT,
    const float* __restrict__ W,  const float* __restrict__ bias,
    const float* __restrict__ gates, const int branch,
    float* __restrict__ acc, u16* __restrict__ tmpT)
{
    __shared__ u16 sA[2][256*64];
    __shared__ u16 sB[2][64*64];

    const int tid = threadIdx.x;
    // XCD-aware block remap (8 XCDs, 1536 blocks, round-robin assignment)
    const int fb_ = blockIdx.x;
    const int s_  = (fb_ & 7) * 192 + (fb_ >> 3);
    const int bt  = s_ >> 2;
    const int n0  = (s_ & 3) * 256;
    const int wv  = tid >> 6, lane = tid & 63;
    const int lr  = lane & 15, lg = lane >> 4;
    const int wrow0 = wv * 64;

    const u16* asrc = adj  + (size_t)n0 * 1024;
    const u16* bsrc = srcT + (size_t)bt * 65536;

    auto stage = [&](int buf, int kt){
        const int m0 = kt * 64;
        #pragma unroll
        for (int i = 0; i < 8; i++){
            const int s = i*256 + tid;
            const int row = s >> 3, kbp = s & 7;
            const int kb = kbp ^ (row & 7);
            GLLDS(asrc + (size_t)row*1024 + m0 + kb*8, &sA[buf][s*8]);
        }
        #pragma unroll
        for (int i = 0; i < 2; i++){
            const int s = i*256 + tid;
            const int row = s >> 3, kbp = s & 7;
            const int kb = kbp ^ (row & 7);
            GLLDS(bsrc + (size_t)row*1024 + m0 + kb*8, &sB[buf][s*8]);
        }
    };

    const f32x4 z4 = {0.f, 0.f, 0.f, 0.f};
    f32x4 c[4][4];
    #pragma unroll
    for (int m = 0; m < 4; m++)
        #pragma unroll
        for (int n = 0; n < 4; n++) c[m][n] = z4;

    stage(0, 0);
    asm volatile("s_waitcnt vmcnt(0)" ::: "memory");
    __syncthreads();

    int cur = 0;
    for (int kt = 0; kt < 16; kt++){
        if (kt < 15) stage(cur ^ 1, kt + 1);
        const u16* A = sA[cur];
        const u16* B = sB[cur];
        short8 af[2][4], bfr[2][4];
        #pragma unroll
        for (int kk = 0; kk < 2; kk++){
            const int kb = lg + kk*4;
            #pragma unroll
            for (int m = 0; m < 4; m++){
                const int row = wrow0 + m*16 + lr;
                af[kk][m] = *(const short8*)&A[row*64 + ((kb ^ (row & 7)) << 3)];
            }
            #pragma unroll
            for (int n = 0; n < 4; n++){
                const int fr = n*16 + lr;
                bfr[kk][n] = *(const short8*)&B[fr*64 + ((kb ^ (fr & 7)) << 3)];
            }
        }
        #pragma unroll
        for (int kk = 0; kk < 2; kk++)
            #pragma unroll
            for (int m = 0; m < 4; m++)
                #pragma unroll
                for (int n = 0; n < 4; n++)
                    c[m][n] = __builtin_amdgcn_mfma_f32_16x16x32_bf16(
                        af[kk][m], bfr[kk][n], c[m][n], 0, 0, 0);
        asm volatile("s_waitcnt vmcnt(0)" ::: "memory");
        __syncthreads();
        cur ^= 1;
    }

    // stash yT (bf16, swizzled) into sA[0]; stage W into sB[0]
    u16* yT = &sA[0][0];
    u16* sW = &sB[0][0];
    #pragma unroll
    for (int m = 0; m < 4; m++)
        #pragma unroll
        for (int n = 0; n < 4; n++){
            const int f = n*16 + lr;
            #pragma unroll
            for (int r = 0; r < 4; r++){
                const int row = wrow0 + m*16 + lg*4 + r;
                yT[row*64 + (((f >> 3) ^ (row & 7)) << 3) + (f & 7)] = f2bf(c[m][n][r]);
            }
        }
    for (int i = tid; i < 4096; i += 256){
        const int o = i >> 6, f = i & 63;
        sW[o*64 + (((f >> 3) ^ (o & 7)) << 3) + (f & 7)] = f2bf(W[i]);
    }
    __syncthreads();

    // coalesced tmp write: thread tid owns node-row tid (reads all-wave yT)
    if (WRITE_TMP){
        const size_t ob = (size_t)bt*65536 + n0 + tid;
        #pragma unroll
        for (int fbk = 0; fbk < 8; fbk++){
            const short8 v = *(const short8*)&yT[tid*64 + ((fbk ^ (tid & 7)) << 3)];
            #pragma unroll
            for (int j = 0; j < 8; j++)
                tmpT[ob + (size_t)(fbk*8 + j)*1024] = (u16)v[j];
        }
    }

    // lin = y @ W^T via MFMA (K = 64)
    f32x4 lin[4][4];
    #pragma unroll
    for (int m = 0; m < 4; m++)
        #pragma unroll
        for (int n = 0; n < 4; n++) lin[m][n] = z4;
    #pragma unroll
    for (int kk = 0; kk < 2; kk++){
        const int kb = lg + kk*4;
        short8 ya[4], wb[4];
        #pragma unroll
        for (int m = 0; m < 4; m++){
            const int row = wrow0 + m*16 + lr;
            ya[m] = *(const short8*)&yT[row*64 + ((kb ^ (row & 7)) << 3)];
        }
        #pragma unroll
        for (int n = 0; n < 4; n++){
            const int o = n*16 + lr;
            wb[n] = *(const short8*)&sW[o*64 + ((kb ^ (o & 7)) << 3)];
        }
        #pragma unroll
        for (int m = 0; m < 4; m++)
            #pragma unroll
            for (int n = 0; n < 4; n++)
                lin[m][n] = __builtin_amdgcn_mfma_f32_16x16x32_bf16(
                    ya[m], wb[n], lin[m][n], 0, 0, 0);
    }

    // acc += g * (lin + bias)
    #pragma unroll
    for (int m = 0; m < 4; m++){
        float g[4];
        #pragma unroll
        for (int r = 0; r < 4; r++){
            const int node = n0 + wrow0 + m*16 + lg*4 + r;
            g[r] = gates[((size_t)bt*1024 + node)*4 + branch];
        }
        #pragma unroll
        for (int n = 0; n < 4; n++){
            const int f  = n*16 + lr;
            const float bv = bias[f];
            #pragma unroll
            for (int r = 0; r < 4; r++){
                const int node = n0 + wrow0 + m*16 + lg*4 + r;
                float* p = &acc[((size_t)bt*1024 + node)*64 + f];
                *p += g[r] * (lin[m][n][r] + bv);
            }
        }
    }
}

// ---------------------------------------------------------------------------
// Finalize: mixed = acc*scale; h = x + gelu(mixed); layernorm
// ---------------------------------------------------------------------------
__global__ __launch_bounds__(256) void k_final(
    const float* __restrict__ x, const u16* __restrict__ scaleb,
    const float* __restrict__ gamma, const float* __restrict__ beta,
    float* __restrict__ out)
{
    const int tid = threadIdx.x;
    const int w = tid >> 6, lane = tid & 63;
    const size_t tok  = (size_t)blockIdx.x*4 + w;
    const size_t base = tok*64 + lane;
    const float mixed = out[base] * b2f(scaleb[base]);
    const float h = x[base] + gelu_exact(mixed);
    float mu = h;
    #pragma unroll
    for (int o = 32; o > 0; o >>= 1) mu += __shfl_xor(mu, o, 64);
    mu *= (1.0f/64.0f);
    const float d = h - mu;
    float v = d*d;
    #pragma unroll
    for (int o = 32; o > 0; o >>= 1) v += __shfl_xor(v, o, 64);
    v *= (1.0f/64.0f);
    out[base] = d * rsqrtf(v + LN_EPS) * gamma[lane] + beta[lane];
}

// ---------------------------------------------------------------------------
extern "C" void kernel_launch(void* const* d_in, const int* in_sizes, int n_in,
                              void* d_out, int out_size, void* d_ws, size_t ws_size,
                              hipStream_t stream)
{
    const float* x      = (const float*)d_in[0];
    const float* a_fwd  = (const float*)d_in[1];
    const float* ctx    = (const float*)d_in[2];
    const float* W_self = (const float*)d_in[3];
    const float* b_self = (const float*)d_in[4];
    const float* W_fwd  = (const float*)d_in[5];
    const float* b_fwd  = (const float*)d_in[6];
    const float* W_bwd  = (const float*)d_in[7];
    const float* b_bwd  = (const float*)d_in[8];
    const float* W_adp  = (const float*)d_in[9];
    const float* b_adp  = (const float*)d_in[10];
    const float* Wg1    = (const float*)d_in[11];
    const float* bg1    = (const float*)d_in[12];
    const float* Wg2    = (const float*)d_in[13];
    const float* bg2    = (const float*)d_in[14];
    const float* Ws1    = (const float*)d_in[15];
    const float* bs1    = (const float*)d_in[16];
    const float* Ws2    = (const float*)d_in[17];
    const float* bs2    = (const float*)d_in[18];
    const float* W_src  = (const float*)d_in[19];
    const float* b_src  = (const float*)d_in[20];
    const float* W_dst  = (const float*)d_in[21];
    const float* b_dst  = (const float*)d_in[22];
    const float* emb_src= (const float*)d_in[23];
    const float* emb_dst= (const float*)d_in[24];
    const float* gamma  = (const float*)d_in[25];
    const float* beta   = (const float*)d_in[26];

    float* out = (float*)d_out;
    char*  w   = (char*)d_ws;
    const size_t MB48 = 50331648ull;
    u16* afwd_bf = (u16*)(w);
    u16* abwd_bf = (u16*)(w + 2097152ull);
    u16* aadp_bf = (u16*)(w + 4194304ull);
    u16* xTp     = (u16*)(w + 6291456ull);
    u16* xTd     = (u16*)(w + 6291456ull + 1*MB48);
    u16* xTs     = (u16*)(w + 6291456ull + 2*MB48);
    u16* tmpT    = (u16*)(w + 6291456ull + 3*MB48);
    u16* scaleb  = (u16*)(w + 6291456ull + 4*MB48);
    float* gates = (float*)(w + 6291456ull + 5*MB48);

    k_adp   <<<1024, 256, 0, stream>>>(emb_src, emb_dst, aadp_bf);
    k_cvt   <<<1024, 256, 0, stream>>>(a_fwd, afwd_bf);
    k_bwd   <<<dim3(32,32), 256, 0, stream>>>(a_fwd, abwd_bf);
    k_gating<<<1536, 256, 0, stream>>>(x, ctx, Wg1,bg1, Wg2,bg2, Ws1,bs1, Ws2,bs2,
                                       W_src,b_src, W_dst,b_dst, W_self,b_self,
                                       gates, scaleb, out, xTp, xTd, xTs);

    k_diffmm<true ><<<1536,256,0,stream>>>(afwd_bf, xTd,  W_fwd,      b_fwd,    gates, 1, out, tmpT);
    k_diffmm<false><<<1536,256,0,stream>>>(afwd_bf, tmpT, W_fwd+4096, b_fwd+64, gates, 1, out, tmpT);
    k_diffmm<true ><<<1536,256,0,stream>>>(abwd_bf, xTs,  W_bwd,      b_bwd,    gates, 2, out, tmpT);
    k_diffmm<false><<<1536,256,0,stream>>>(abwd_bf, tmpT, W_bwd+4096, b_bwd+64, gates, 2, out, tmpT);
    k_diffmm<true ><<<1536,256,0,stream>>>(aadp_bf, xTp,  W_adp,      b_adp,    gates, 3, out, tmpT);
    k_diffmm<false><<<1536,256,0,stream>>>(aadp_bf, tmpT, W_adp+4096, b_adp+64, gates, 3, out, tmpT);

    k_final <<<98304, 256, 0, stream>>>(x, scaleb, gamma, beta, out);
}

// Round 7
// 1052.544 us; speedup vs baseline: 1.3922x; 1.0022x over previous
//
#include <hip/hip_runtime.h>
#include <math.h>

typedef unsigned short u16;
typedef short short8 __attribute__((ext_vector_type(8)));
typedef float f32x4 __attribute__((ext_vector_type(4)));

#define LN_EPS 1e-5f

__device__ __forceinline__ float gelu_exact(float x){
    return 0.5f * x * (1.0f + erff(x * 0.70710678118654752f));
}
__device__ __forceinline__ float sigmoidf_(float x){
    return 1.0f / (1.0f + __expf(-x));
}
__device__ __forceinline__ u16 f2bf(float f){            // RTNE f32->bf16
    unsigned u = __float_as_uint(f);
    u += 0x7fffu + ((u >> 16) & 1u);
    return (u16)(u >> 16);
}
__device__ __forceinline__ float b2f(u16 u){
    return __uint_as_float(((unsigned)u) << 16);
}

#define GLLDS(gp, lp) __builtin_amdgcn_global_load_lds( \
    (const __attribute__((address_space(1))) unsigned int*)(const void*)(gp), \
    (__attribute__((address_space(3))) unsigned int*)(void*)(lp), 16, 0, 0)

// ---------------------------------------------------------------------------
// a_adp = softmax(relu(emb_src @ emb_dst^T)) -> bf16 [1024][1024]
// ---------------------------------------------------------------------------
__global__ __launch_bounds__(256) void k_adp(const float* __restrict__ es,
                                             const float* __restrict__ ed,
                                             u16* __restrict__ aadp){
    __shared__ float srow[1024];
    __shared__ float s_es[16];
    __shared__ float sredm[4];
    __shared__ float sreds[4];
    const int n   = blockIdx.x;
    const int tid = threadIdx.x;
    const int wid = tid >> 6, lane = tid & 63;
    if (tid < 16) s_es[tid] = es[n*16 + tid];
    __syncthreads();
    float lmax = 0.0f;
    for (int m = tid; m < 1024; m += 256){
        const float* edm = ed + m*16;
        float z = 0.f;
        #pragma unroll
        for (int r = 0; r < 16; r++) z = fmaf(s_es[r], edm[r], z);
        z = fmaxf(z, 0.0f);
        srow[m] = z;
        lmax = fmaxf(lmax, z);
    }
    #pragma unroll
    for (int o = 32; o > 0; o >>= 1) lmax = fmaxf(lmax, __shfl_xor(lmax, o, 64));
    if (lane == 0) sredm[wid] = lmax;
    __syncthreads();
    const float tmax = fmaxf(fmaxf(sredm[0], sredm[1]), fmaxf(sredm[2], sredm[3]));
    float lsum = 0.f;
    for (int m = tid; m < 1024; m += 256){
        float e = expf(srow[m] - tmax);
        srow[m] = e;
        lsum += e;
    }
    #pragma unroll
    for (int o = 32; o > 0; o >>= 1) lsum += __shfl_xor(lsum, o, 64);
    if (lane == 0) sreds[wid] = lsum;
    __syncthreads();
    const float inv = 1.0f / (sreds[0] + sreds[1] + sreds[2] + sreds[3]);
    for (int m = tid; m < 1024; m += 256) aadp[(size_t)n*1024 + m] = f2bf(srow[m] * inv);
}

// ---------------------------------------------------------------------------
// afwd = bf16(a_fwd);  abwd[n][m] = bf16(a_fwd[m][n])   (one pass)
// ---------------------------------------------------------------------------
__global__ __launch_bounds__(256) void k_cvtbwd(const float* __restrict__ a,
                                                u16* __restrict__ afwd,
                                                u16* __restrict__ abwd){
    __shared__ float t[32][33];
    const int bx = blockIdx.x*32, by = blockIdx.y*32;
    const int tx = threadIdx.x & 31, ty = threadIdx.x >> 5;
    #pragma unroll
    for (int i = 0; i < 4; i++){
        const float v = a[(size_t)(by + ty + 8*i)*1024 + bx + tx];
        t[ty + 8*i][tx] = v;
        afwd[(size_t)(by + ty + 8*i)*1024 + bx + tx] = f2bf(v);
    }
    __syncthreads();
    #pragma unroll
    for (int i = 0; i < 4; i++)
        abwd[(size_t)(bx + ty + 8*i)*1024 + by + tx] = f2bf(t[tx][ty + 8*i]);
}

// ---------------------------------------------------------------------------
// MFMA gating kernel — 128 tokens/block, ~34 KB LDS -> 4 blocks/CU.
// ---------------------------------------------------------------------------
__global__ __launch_bounds__(256, 4) void k_gating(
    const float* __restrict__ x,    const float* __restrict__ ctx,
    const float* __restrict__ Wg1,  const float* __restrict__ bg1,
    const float* __restrict__ Wg2,  const float* __restrict__ bg2,
    const float* __restrict__ Ws1,  const float* __restrict__ bs1,
    const float* __restrict__ Ws2,  const float* __restrict__ bs2,
    const float* __restrict__ Wsrc, const float* __restrict__ bsrc,
    const float* __restrict__ Wdst, const float* __restrict__ bdst,
    const float* __restrict__ Wself,const float* __restrict__ bself,
    float* __restrict__ gates, u16* __restrict__ scaleb,
    float* __restrict__ acc,
    u16* __restrict__ xTp, u16* __restrict__ xTd, u16* __restrict__ xTs)
{
    __shared__ u16 H1[8192];      // 16 KB
    __shared__ u16 H2[8192];      // 16 KB
    __shared__ float sgate[128], dgate[128];

    const int tid  = threadIdx.x;
    const int wv   = tid >> 6, lane = tid & 63;
    const int lr   = lane & 15, lg = lane >> 4;
    const int wtok = wv * 32;
    const int tokbase = blockIdx.x * 128;
    const int bt = blockIdx.x >> 3;
    const int n0 = (blockIdx.x & 7) * 128;

    auto stage_coop = [&](u16* H, const float* g){
        #pragma unroll
        for (int i = 0; i < 8; i++){
            const int fid = i*256 + tid;
            const int t = fid >> 4, q = fid & 15;
            const float4 v = *(const float4*)&g[(size_t)t*64 + q*4];
            ushort4 s;
            s.x = f2bf(v.x); s.y = f2bf(v.y); s.z = f2bf(v.z); s.w = f2bf(v.w);
            *(ushort4*)&H[t*64 + ((((q>>1) ^ (t & 7)) << 3) | ((q & 1)*4))] = s;
        }
    };
    auto afrag = [&](const u16* H, int row, int kb)->short8{
        return *(const short8*)&H[wv*2048 + row*64 + ((kb ^ (row & 7)) << 3)];
    };
    auto wfrag = [&](const float* W, int o, int kb8)->short8{
        const float4 a = *(const float4*)&W[o*64 + kb8];
        const float4 b = *(const float4*)&W[o*64 + kb8 + 4];
        short8 s;
        s[0]=f2bf(a.x); s[1]=f2bf(a.y); s[2]=f2bf(a.z); s[3]=f2bf(a.w);
        s[4]=f2bf(b.x); s[5]=f2bf(b.y); s[6]=f2bf(b.z); s[7]=f2bf(b.w);
        return s;
    };
    auto gemm32 = [&](const u16* Hs, const float* W, const float* bias, f32x4 (&c)[2][4]){
        #pragma unroll
        for (int n = 0; n < 4; n++){
            const float bv = bias[n*16 + lr];
            #pragma unroll
            for (int m = 0; m < 2; m++){ f32x4 t = {bv,bv,bv,bv}; c[m][n] = t; }
        }
        #pragma unroll
        for (int kk = 0; kk < 2; kk++){
            short8 a[2];
            #pragma unroll
            for (int m = 0; m < 2; m++) a[m] = afrag(Hs, m*16 + lr, kk*4 + lg);
            #pragma unroll
            for (int n = 0; n < 4; n++){
                const short8 w = wfrag(W, n*16 + lr, kk*32 + lg*8);
                #pragma unroll
                for (int m = 0; m < 2; m++)
                    c[m][n] = __builtin_amdgcn_mfma_f32_16x16x32_bf16(a[m], w, c[m][n], 0,0,0);
            }
        }
    };
    auto storeH = [&](u16* Hd, f32x4 (&c)[2][4]){
        #pragma unroll
        for (int m = 0; m < 2; m++)
            #pragma unroll
            for (int n = 0; n < 4; n++){
                const int f = n*16 + lr;
                #pragma unroll
                for (int r = 0; r < 4; r++){
                    const int t = m*16 + lg*4 + r;
                    Hd[wv*2048 + t*64 + ((((f>>3) ^ (t & 7)) << 3) | (f & 7))] = f2bf(c[m][n][r]);
                }
            }
    };

    stage_coop(H1, ctx + (size_t)tokbase*64);
    __syncthreads();

    f32x4 c[2][4];

    // hg = gelu(ctx @ Wg1^T + bg1) -> H2
    gemm32(H1, Wg1, bg1, c);
    #pragma unroll
    for (int m = 0; m < 2; m++)
        #pragma unroll
        for (int n = 0; n < 4; n++)
            #pragma unroll
            for (int r = 0; r < 4; r++) c[m][n][r] = gelu_exact(c[m][n][r]);
    storeH(H2, c);

    // src/dst gates
    {
        f32x4 c2[2];
        const float bv = (lr == 0) ? bsrc[0] : (lr == 1 ? bdst[0] : 0.f);
        #pragma unroll
        for (int m = 0; m < 2; m++){ f32x4 t = {bv,bv,bv,bv}; c2[m] = t; }
        #pragma unroll
        for (int kk = 0; kk < 2; kk++){
            short8 a[2];
            #pragma unroll
            for (int m = 0; m < 2; m++) a[m] = afrag(H1, m*16 + lr, kk*4 + lg);
            short8 w = {0,0,0,0,0,0,0,0};
            if (lr == 0) w = wfrag(Wsrc, 0, kk*32 + lg*8);
            else if (lr == 1) w = wfrag(Wdst, 0, kk*32 + lg*8);
            #pragma unroll
            for (int m = 0; m < 2; m++)
                c2[m] = __builtin_amdgcn_mfma_f32_16x16x32_bf16(a[m], w, c2[m], 0,0,0);
        }
        #pragma unroll
        for (int m = 0; m < 2; m++)
            #pragma unroll
            for (int r = 0; r < 4; r++){
                const int t = wtok + m*16 + lg*4 + r;
                const float v = sigmoidf_(c2[m][r]);
                if (lr == 0) sgate[t] = v;
                if (lr == 1) dgate[t] = v;
            }
    }

    // hs = gelu(ctx @ Ws1^T + bs1) -> H1 (wave-private slice, safe in place)
    gemm32(H1, Ws1, bs1, c);
    #pragma unroll
    for (int m = 0; m < 2; m++)
        #pragma unroll
        for (int n = 0; n < 4; n++)
            #pragma unroll
            for (int r = 0; r < 4; r++) c[m][n][r] = gelu_exact(c[m][n][r]);
    storeH(H1, c);

    // gates = sigmoid(hg @ Wg2^T + bg2)
    float g0[2][4];
    {
        f32x4 c3[2];
        const float bv = (lr < 4) ? bg2[lr] : 0.f;
        #pragma unroll
        for (int m = 0; m < 2; m++){ f32x4 t = {bv,bv,bv,bv}; c3[m] = t; }
        #pragma unroll
        for (int kk = 0; kk < 2; kk++){
            short8 a[2];
            #pragma unroll
            for (int m = 0; m < 2; m++) a[m] = afrag(H2, m*16 + lr, kk*4 + lg);
            short8 w = {0,0,0,0,0,0,0,0};
            if (lr < 4) w = wfrag(Wg2, lr, kk*32 + lg*8);
            #pragma unroll
            for (int m = 0; m < 2; m++)
                c3[m] = __builtin_amdgcn_mfma_f32_16x16x32_bf16(a[m], w, c3[m], 0,0,0);
        }
        #pragma unroll
        for (int m = 0; m < 2; m++)
            #pragma unroll
            for (int r = 0; r < 4; r++){
                const float v = sigmoidf_(c3[m][r]);
                if (lr < 4)
                    gates[(size_t)(tokbase + wtok + m*16 + lg*4 + r)*4 + lr] = v;
                g0[m][r] = __shfl(v, lane & 48, 64);
            }
    }

    // scale = sigmoid(hs @ Ws2^T + bs2) -> H1 -> coalesced store
    gemm32(H1, Ws2, bs2, c);
    #pragma unroll
    for (int m = 0; m < 2; m++)
        #pragma unroll
        for (int n = 0; n < 4; n++)
            #pragma unroll
            for (int r = 0; r < 4; r++) c[m][n][r] = sigmoidf_(c[m][n][r]);
    storeH(H1, c);
    {
        #pragma unroll
        for (int it = 0; it < 4; it++){
            const int r2  = wtok + it*8 + (lane >> 3);
            const int sub = lane & 7;
            const short8 v = *(const short8*)&H1[r2*64 + ((sub ^ (r2 & 7)) << 3)];
            *(short8*)&scaleb[(size_t)(tokbase + r2)*64 + sub*8] = v;
        }
    }

    __syncthreads();
    stage_coop(H2, x + (size_t)tokbase*64);
    __syncthreads();

    // self = x @ Wself^T + bself; acc = g0 * self
    gemm32(H2, Wself, bself, c);
    #pragma unroll
    for (int m = 0; m < 2; m++)
        #pragma unroll
        for (int n = 0; n < 4; n++)
            #pragma unroll
            for (int r = 0; r < 4; r++)
                acc[(size_t)(tokbase + wtok + m*16 + lg*4 + r)*64 + n*16 + lr]
                    = g0[m][r] * c[m][n][r];

    // coalesced f-major transposed outputs
    {
        const int tok  = tid & 127;
        const int fbh  = tid >> 7;            // 0 or 1
        const float dg = dgate[tok], sg = sgate[tok];
        const size_t ob = (size_t)bt*65536 + n0 + tok;
        #pragma unroll
        for (int q = 0; q < 4; q++){
            const int fb = fbh*4 + q;
            const short8 v = *(const short8*)&H2[tok*64 + ((fb ^ (tok & 7)) << 3)];
            #pragma unroll
            for (int j = 0; j < 8; j++){
                const u16 raw = (u16)v[j];
                const float xv = b2f(raw);
                const size_t o = ob + (size_t)(fb*8 + j)*1024;
                xTp[o] = raw;
                xTd[o] = f2bf(xv * dg);
                xTs[o] = f2bf(xv * sg);
            }
        }
    }
}

// ---------------------------------------------------------------------------
// MFMA diffusion GEMM + fused linear/gate epilogue (r5-proven structure).
//  WRITE_TMP: also write y (transposed bf16, coalesced) for the next step.
//  FINAL: instead of acc RMW, do scale*gelu+residual+layernorm -> acc (out).
// XCD-aware remap keeps one bt's 4 n-tiles on one XCD (srcT L2 reuse).
// ---------------------------------------------------------------------------
template<bool WRITE_TMP, bool FINAL>
__global__ __launch_bounds__(256, 2) void k_diffmm(
    const u16* __restrict__ adj,  const u16* __restrict__ srcT,
    const float* __restrict__ W,  const float* __restrict__ bias,
    const float* __restrict__ gates, const int branch,
    float* __restrict__ acc, u16* __restrict__ tmpT,
    const float* __restrict__ x, const u16* __restrict__ scaleb,
    const float* __restrict__ gamma, const float* __restrict__ beta)
{
    __shared__ u16 sA[2][256*64];
    __shared__ u16 sB[2][64*64];

    const int tid = threadIdx.x;
    const int fb_ = blockIdx.x;
    const int s_  = (fb_ & 7) * 192 + (fb_ >> 3);
    const int bt  = s_ >> 2;
    const int n0  = (s_ & 3) * 256;
    const int wv  = tid >> 6, lane = tid & 63;
    const int lr  = lane & 15, lg = lane >> 4;
    const int wrow0 = wv * 64;

    const u16* asrc = adj  + (size_t)n0 * 1024;
    const u16* bsrc = srcT + (size_t)bt * 65536;

    auto stage = [&](int buf, int kt){
        const int m0 = kt * 64;
        #pragma unroll
        for (int i = 0; i < 8; i++){
            const int s = i*256 + tid;
            const int row = s >> 3, kbp = s & 7;
            const int kb = kbp ^ (row & 7);
            GLLDS(asrc + (size_t)row*1024 + m0 + kb*8, &sA[buf][s*8]);
        }
        #pragma unroll
        for (int i = 0; i < 2; i++){
            const int s = i*256 + tid;
            const int row = s >> 3, kbp = s & 7;
            const int kb = kbp ^ (row & 7);
            GLLDS(bsrc + (size_t)row*1024 + m0 + kb*8, &sB[buf][s*8]);
        }
    };

    const f32x4 z4 = {0.f, 0.f, 0.f, 0.f};
    f32x4 c[4][4];
    #pragma unroll
    for (int m = 0; m < 4; m++)
        #pragma unroll
        for (int n = 0; n < 4; n++) c[m][n] = z4;

    stage(0, 0);
    asm volatile("s_waitcnt vmcnt(0)" ::: "memory");
    __syncthreads();

    int cur = 0;
    for (int kt = 0; kt < 16; kt++){
        if (kt < 15) stage(cur ^ 1, kt + 1);
        const u16* A = sA[cur];
        const u16* B = sB[cur];
        short8 af[2][4], bfr[2][4];
        #pragma unroll
        for (int kk = 0; kk < 2; kk++){
            const int kb = lg + kk*4;
            #pragma unroll
            for (int m = 0; m < 4; m++){
                const int row = wrow0 + m*16 + lr;
                af[kk][m] = *(const short8*)&A[row*64 + ((kb ^ (row & 7)) << 3)];
            }
            #pragma unroll
            for (int n = 0; n < 4; n++){
                const int fr = n*16 + lr;
                bfr[kk][n] = *(const short8*)&B[fr*64 + ((kb ^ (fr & 7)) << 3)];
            }
        }
        #pragma unroll
        for (int kk = 0; kk < 2; kk++)
            #pragma unroll
            for (int m = 0; m < 4; m++)
                #pragma unroll
                for (int n = 0; n < 4; n++)
                    c[m][n] = __builtin_amdgcn_mfma_f32_16x16x32_bf16(
                        af[kk][m], bfr[kk][n], c[m][n], 0, 0, 0);
        asm volatile("s_waitcnt vmcnt(0)" ::: "memory");
        __syncthreads();
        cur ^= 1;
    }

    // stash yT (bf16, swizzled) into sA[0]; stage W into sB[0]
    u16* yT = &sA[0][0];
    u16* sW = &sB[0][0];
    #pragma unroll
    for (int m = 0; m < 4; m++)
        #pragma unroll
        for (int n = 0; n < 4; n++){
            const int f = n*16 + lr;
            #pragma unroll
            for (int r = 0; r < 4; r++){
                const int row = wrow0 + m*16 + lg*4 + r;
                yT[row*64 + (((f >> 3) ^ (row & 7)) << 3) + (f & 7)] = f2bf(c[m][n][r]);
            }
        }
    for (int i = tid; i < 4096; i += 256){
        const int o = i >> 6, f = i & 63;
        sW[o*64 + (((f >> 3) ^ (o & 7)) << 3) + (f & 7)] = f2bf(W[i]);
    }
    __syncthreads();

    // coalesced tmp write: thread tid owns node-row tid (reads all-wave yT)
    if (WRITE_TMP){
        const size_t ob = (size_t)bt*65536 + n0 + tid;
        #pragma unroll
        for (int fbk = 0; fbk < 8; fbk++){
            const short8 v = *(const short8*)&yT[tid*64 + ((fbk ^ (tid & 7)) << 3)];
            #pragma unroll
            for (int j = 0; j < 8; j++)
                tmpT[ob + (size_t)(fbk*8 + j)*1024] = (u16)v[j];
        }
    }

    // lin = y @ W^T via MFMA (K = 64)
    f32x4 lin[4][4];
    #pragma unroll
    for (int m = 0; m < 4; m++)
        #pragma unroll
        for (int n = 0; n < 4; n++) lin[m][n] = z4;
    #pragma unroll
    for (int kk = 0; kk < 2; kk++){
        const int kb = lg + kk*4;
        short8 ya[4], wb[4];
        #pragma unroll
        for (int m = 0; m < 4; m++){
            const int row = wrow0 + m*16 + lr;
            ya[m] = *(const short8*)&yT[row*64 + ((kb ^ (row & 7)) << 3)];
        }
        #pragma unroll
        for (int n = 0; n < 4; n++){
            const int o = n*16 + lr;
            wb[n] = *(const short8*)&sW[o*64 + ((kb ^ (o & 7)) << 3)];
        }
        #pragma unroll
        for (int m = 0; m < 4; m++)
            #pragma unroll
            for (int n = 0; n < 4; n++)
                lin[m][n] = __builtin_amdgcn_mfma_f32_16x16x32_bf16(
                    ya[m], wb[n], lin[m][n], 0, 0, 0);
    }

    if constexpr (!FINAL){
        // acc += g * (lin + bias)
        #pragma unroll
        for (int m = 0; m < 4; m++){
            float g[4];
            #pragma unroll
            for (int r = 0; r < 4; r++){
                const int node = n0 + wrow0 + m*16 + lg*4 + r;
                g[r] = gates[((size_t)bt*1024 + node)*4 + branch];
            }
            #pragma unroll
            for (int n = 0; n < 4; n++){
                const int f  = n*16 + lr;
                const float bv = bias[f];
                #pragma unroll
                for (int r = 0; r < 4; r++){
                    const int node = n0 + wrow0 + m*16 + lg*4 + r;
                    float* p = &acc[((size_t)bt*1024 + node)*64 + f];
                    *p += g[r] * (lin[m][n][r] + bv);
                }
            }
        }
    } else {
        // fused final: mixed=(acc+g*(lin+b))*scale; h=x+gelu(mixed); LN -> acc
        #pragma unroll
        for (int m = 0; m < 4; m++){
            #pragma unroll
            for (int r = 0; r < 4; r++){
                const int node = n0 + wrow0 + m*16 + lg*4 + r;
                const size_t tok = (size_t)bt*1024 + node;
                const float g = gates[tok*4 + branch];
                float h[4];
                #pragma unroll
                for (int n = 0; n < 4; n++){
                    const int f = n*16 + lr;
                    const float a = acc[tok*64 + f] + g * (lin[m][n][r] + bias[f]);
                    const float mixed = a * b2f(scaleb[tok*64 + f]);
                    h[n] = x[tok*64 + f] + gelu_exact(mixed);
                }
                float s = h[0] + h[1] + h[2] + h[3];
                #pragma unroll
                for (int o = 8; o > 0; o >>= 1) s += __shfl_xor(s, o, 64);
                const float mu = s * (1.0f/64.0f);
                float vs = 0.f;
                #pragma unroll
                for (int n = 0; n < 4; n++){ const float d = h[n] - mu; vs += d*d; }
                #pragma unroll
                for (int o = 8; o > 0; o >>= 1) vs += __shfl_xor(vs, o, 64);
                const float inv = rsqrtf(vs * (1.0f/64.0f) + LN_EPS);
                #pragma unroll
                for (int n = 0; n < 4; n++){
                    const int f = n*16 + lr;
                    acc[tok*64 + f] = (h[n] - mu) * inv * gamma[f] + beta[f];
                }
            }
        }
    }
}

// ---------------------------------------------------------------------------
extern "C" void kernel_launch(void* const* d_in, const int* in_sizes, int n_in,
                              void* d_out, int out_size, void* d_ws, size_t ws_size,
                              hipStream_t stream)
{
    const float* x      = (const float*)d_in[0];
    const float* a_fwd  = (const float*)d_in[1];
    const float* ctx    = (const float*)d_in[2];
    const float* W_self = (const float*)d_in[3];
    const float* b_self = (const float*)d_in[4];
    const float* W_fwd  = (const float*)d_in[5];
    const float* b_fwd  = (const float*)d_in[6];
    const float* W_bwd  = (const float*)d_in[7];
    const float* b_bwd  = (const float*)d_in[8];
    const float* W_adp  = (const float*)d_in[9];
    const float* b_adp  = (const float*)d_in[10];
    const float* Wg1    = (const float*)d_in[11];
    const float* bg1    = (const float*)d_in[12];
    const float* Wg2    = (const float*)d_in[13];
    const float* bg2    = (const float*)d_in[14];
    const float* Ws1    = (const float*)d_in[15];
    const float* bs1    = (const float*)d_in[16];
    const float* Ws2    = (const float*)d_in[17];
    const float* bs2    = (const float*)d_in[18];
    const float* W_src  = (const float*)d_in[19];
    const float* b_src  = (const float*)d_in[20];
    const float* W_dst  = (const float*)d_in[21];
    const float* b_dst  = (const float*)d_in[22];
    const float* emb_src= (const float*)d_in[23];
    const float* emb_dst= (const float*)d_in[24];
    const float* gamma  = (const float*)d_in[25];
    const float* beta   = (const float*)d_in[26];

    float* out = (float*)d_out;
    char*  w   = (char*)d_ws;
    const size_t MB48 = 50331648ull;
    u16* afwd_bf = (u16*)(w);
    u16* abwd_bf = (u16*)(w + 2097152ull);
    u16* aadp_bf = (u16*)(w + 4194304ull);
    u16* xTp     = (u16*)(w + 6291456ull);
    u16* xTd     = (u16*)(w + 6291456ull + 1*MB48);
    u16* xTs     = (u16*)(w + 6291456ull + 2*MB48);
    u16* tmpT    = (u16*)(w + 6291456ull + 3*MB48);
    u16* scaleb  = (u16*)(w + 6291456ull + 4*MB48);
    float* gates = (float*)(w + 6291456ull + 5*MB48);

    k_adp   <<<1024, 256, 0, stream>>>(emb_src, emb_dst, aadp_bf);
    k_cvtbwd<<<dim3(32,32), 256, 0, stream>>>(a_fwd, afwd_bf, abwd_bf);
    k_gating<<<3072, 256, 0, stream>>>(x, ctx, Wg1,bg1, Wg2,bg2, Ws1,bs1, Ws2,bs2,
                                       W_src,b_src, W_dst,b_dst, W_self,b_self,
                                       gates, scaleb, out, xTp, xTd, xTs);

    k_diffmm<true ,false><<<1536,256,0,stream>>>(afwd_bf, xTd,  W_fwd,      b_fwd,
                                                 gates, 1, out, tmpT,
                                                 nullptr, nullptr, nullptr, nullptr);
    k_diffmm<false,false><<<1536,256,0,stream>>>(afwd_bf, tmpT, W_fwd+4096, b_fwd+64,
                                                 gates, 1, out, nullptr,
                                                 nullptr, nullptr, nullptr, nullptr);
    k_diffmm<true ,false><<<1536,256,0,stream>>>(abwd_bf, xTs,  W_bwd,      b_bwd,
                                                 gates, 2, out, tmpT,
                                                 nullptr, nullptr, nullptr, nullptr);
    k_diffmm<false,false><<<1536,256,0,stream>>>(abwd_bf, tmpT, W_bwd+4096, b_bwd+64,
                                                 gates, 2, out, nullptr,
                                                 nullptr, nullptr, nullptr, nullptr);
    k_diffmm<true ,false><<<1536,256,0,stream>>>(aadp_bf, xTp,  W_adp,      b_adp,
                                                 gates, 3, out, tmpT,
                                                 nullptr, nullptr, nullptr, nullptr);
    k_diffmm<false,true ><<<1536,256,0,stream>>>(aadp_bf, tmpT, W_adp+4096, b_adp+64,
                                                 gates, 3, out, nullptr,
                                                 x, scaleb, gamma, beta);
}

// Round 8
// 986.033 us; speedup vs baseline: 1.4861x; 1.0675x over previous
//
#include <hip/hip_runtime.h>
#include <math.h>

typedef unsigned short u16;
typedef short short8 __attribute__((ext_vector_type(8)));
typedef float f32x4 __attribute__((ext_vector_type(4)));

#define LN_EPS 1e-5f

__device__ __forceinline__ float gelu_exact(float x){
    return 0.5f * x * (1.0f + erff(x * 0.70710678118654752f));
}
__device__ __forceinline__ float sigmoidf_(float x){
    return 1.0f / (1.0f + __expf(-x));
}
__device__ __forceinline__ u16 f2bf(float f){            // RTNE f32->bf16
    unsigned u = __float_as_uint(f);
    u += 0x7fffu + ((u >> 16) & 1u);
    return (u16)(u >> 16);
}
__device__ __forceinline__ float b2f(u16 u){
    return __uint_as_float(((unsigned)u) << 16);
}

#define GLLDS(gp, lp) __builtin_amdgcn_global_load_lds( \
    (const __attribute__((address_space(1))) unsigned int*)(const void*)(gp), \
    (__attribute__((address_space(3))) unsigned int*)(void*)(lp), 16, 0, 0)

// ---------------------------------------------------------------------------
// One-time: convert all weight matrices to plain bf16 into wbf.
// Layout (u16 offsets): 0 Wg1 | 4096 Ws1 | 8192 Ws2 | 12288 Wself |
// 16384 Wfwd(2x) | 24576 Wbwd(2x) | 32768 Wadp(2x) | 40960 Wg2 |
// 41216 Wsrc | 41280 Wdst   (total 41344)
// ---------------------------------------------------------------------------
__global__ __launch_bounds__(256) void k_prep(
    const float* __restrict__ Wg1, const float* __restrict__ Ws1,
    const float* __restrict__ Ws2, const float* __restrict__ Wself,
    const float* __restrict__ Wg2, const float* __restrict__ Wsrc,
    const float* __restrict__ Wdst, const float* __restrict__ Wfwd,
    const float* __restrict__ Wbwd, const float* __restrict__ Wadp,
    u16* __restrict__ wbf)
{
    const int i = blockIdx.x*256 + threadIdx.x;
    if (i >= 41344) return;
    const float* src; int off;
    if      (i < 4096)  { src = Wg1;  off = 0; }
    else if (i < 8192)  { src = Ws1;  off = 4096; }
    else if (i < 12288) { src = Ws2;  off = 8192; }
    else if (i < 16384) { src = Wself;off = 12288; }
    else if (i < 24576) { src = Wfwd; off = 16384; }
    else if (i < 32768) { src = Wbwd; off = 24576; }
    else if (i < 40960) { src = Wadp; off = 32768; }
    else if (i < 41216) { src = Wg2;  off = 40960; }
    else if (i < 41280) { src = Wsrc; off = 41216; }
    else                { src = Wdst; off = 41280; }
    wbf[i] = f2bf(src[i - off]);
}

// ---------------------------------------------------------------------------
// a_adp = softmax(relu(emb_src @ emb_dst^T)) -> bf16 [1024][1024]
// ---------------------------------------------------------------------------
__global__ __launch_bounds__(256) void k_adp(const float* __restrict__ es,
                                             const float* __restrict__ ed,
                                             u16* __restrict__ aadp){
    __shared__ float srow[1024];
    __shared__ float s_es[16];
    __shared__ float sredm[4];
    __shared__ float sreds[4];
    const int n   = blockIdx.x;
    const int tid = threadIdx.x;
    const int wid = tid >> 6, lane = tid & 63;
    if (tid < 16) s_es[tid] = es[n*16 + tid];
    __syncthreads();
    float lmax = 0.0f;
    for (int m = tid; m < 1024; m += 256){
        const float* edm = ed + m*16;
        float z = 0.f;
        #pragma unroll
        for (int r = 0; r < 16; r++) z = fmaf(s_es[r], edm[r], z);
        z = fmaxf(z, 0.0f);
        srow[m] = z;
        lmax = fmaxf(lmax, z);
    }
    #pragma unroll
    for (int o = 32; o > 0; o >>= 1) lmax = fmaxf(lmax, __shfl_xor(lmax, o, 64));
    if (lane == 0) sredm[wid] = lmax;
    __syncthreads();
    const float tmax = fmaxf(fmaxf(sredm[0], sredm[1]), fmaxf(sredm[2], sredm[3]));
    float lsum = 0.f;
    for (int m = tid; m < 1024; m += 256){
        float e = expf(srow[m] - tmax);
        srow[m] = e;
        lsum += e;
    }
    #pragma unroll
    for (int o = 32; o > 0; o >>= 1) lsum += __shfl_xor(lsum, o, 64);
    if (lane == 0) sreds[wid] = lsum;
    __syncthreads();
    const float inv = 1.0f / (sreds[0] + sreds[1] + sreds[2] + sreds[3]);
    for (int m = tid; m < 1024; m += 256) aadp[(size_t)n*1024 + m] = f2bf(srow[m] * inv);
}

// ---------------------------------------------------------------------------
// afwd = bf16(a_fwd);  abwd[n][m] = bf16(a_fwd[m][n])   (one pass)
// ---------------------------------------------------------------------------
__global__ __launch_bounds__(256) void k_cvtbwd(const float* __restrict__ a,
                                                u16* __restrict__ afwd,
                                                u16* __restrict__ abwd){
    __shared__ float t[32][33];
    const int bx = blockIdx.x*32, by = blockIdx.y*32;
    const int tx = threadIdx.x & 31, ty = threadIdx.x >> 5;
    #pragma unroll
    for (int i = 0; i < 4; i++){
        const float v = a[(size_t)(by + ty + 8*i)*1024 + bx + tx];
        t[ty + 8*i][tx] = v;
        afwd[(size_t)(by + ty + 8*i)*1024 + bx + tx] = f2bf(v);
    }
    __syncthreads();
    #pragma unroll
    for (int i = 0; i < 4; i++)
        abwd[(size_t)(bx + ty + 8*i)*1024 + by + tx] = f2bf(t[tx][ty + 8*i]);
}

// ---------------------------------------------------------------------------
// MFMA gating kernel — 128 tokens/block; bf16 weights read direct from wbf.
// Outputs: gates(f32), scaleb(bf16), accb = bf16(g0*self), xTp/xTd/xTs.
// ---------------------------------------------------------------------------
__global__ __launch_bounds__(256, 4) void k_gating(
    const float* __restrict__ x,    const float* __restrict__ ctx,
    const u16* __restrict__ wg1,  const float* __restrict__ bg1,
    const u16* __restrict__ wg2,  const float* __restrict__ bg2,
    const u16* __restrict__ ws1,  const float* __restrict__ bs1,
    const u16* __restrict__ ws2,  const float* __restrict__ bs2,
    const u16* __restrict__ wsrc, const float* __restrict__ bsrc,
    const u16* __restrict__ wdst, const float* __restrict__ bdst,
    const u16* __restrict__ wself,const float* __restrict__ bself,
    float* __restrict__ gates, u16* __restrict__ scaleb,
    u16* __restrict__ accb,
    u16* __restrict__ xTp, u16* __restrict__ xTd, u16* __restrict__ xTs)
{
    __shared__ u16 H1[8192];      // 16 KB
    __shared__ u16 H2[8192];      // 16 KB
    __shared__ float sgate[128], dgate[128];

    const int tid  = threadIdx.x;
    const int wv   = tid >> 6, lane = tid & 63;
    const int lr   = lane & 15, lg = lane >> 4;
    const int wtok = wv * 32;
    const int tokbase = blockIdx.x * 128;
    const int bt = blockIdx.x >> 3;
    const int n0 = (blockIdx.x & 7) * 128;

    auto stage_coop = [&](u16* H, const float* g){
        #pragma unroll
        for (int i = 0; i < 8; i++){
            const int fid = i*256 + tid;
            const int t = fid >> 4, q = fid & 15;
            const float4 v = *(const float4*)&g[(size_t)t*64 + q*4];
            ushort4 s;
            s.x = f2bf(v.x); s.y = f2bf(v.y); s.z = f2bf(v.z); s.w = f2bf(v.w);
            *(ushort4*)&H[t*64 + ((((q>>1) ^ (t & 7)) << 3) | ((q & 1)*4))] = s;
        }
    };
    auto afrag = [&](const u16* H, int row, int kb)->short8{
        return *(const short8*)&H[wv*2048 + row*64 + ((kb ^ (row & 7)) << 3)];
    };
    auto wfrag = [&](const u16* W, int o, int kb8)->short8{
        return *(const short8*)&W[o*64 + kb8];
    };
    auto gemm32 = [&](const u16* Hs, const u16* W, const float* bias, f32x4 (&c)[2][4]){
        #pragma unroll
        for (int n = 0; n < 4; n++){
            const float bv = bias[n*16 + lr];
            #pragma unroll
            for (int m = 0; m < 2; m++){ f32x4 t = {bv,bv,bv,bv}; c[m][n] = t; }
        }
        #pragma unroll
        for (int kk = 0; kk < 2; kk++){
            short8 a[2];
            #pragma unroll
            for (int m = 0; m < 2; m++) a[m] = afrag(Hs, m*16 + lr, kk*4 + lg);
            #pragma unroll
            for (int n = 0; n < 4; n++){
                const short8 w = wfrag(W, n*16 + lr, kk*32 + lg*8);
                #pragma unroll
                for (int m = 0; m < 2; m++)
                    c[m][n] = __builtin_amdgcn_mfma_f32_16x16x32_bf16(a[m], w, c[m][n], 0,0,0);
            }
        }
    };
    auto storeH = [&](u16* Hd, f32x4 (&c)[2][4]){
        #pragma unroll
        for (int m = 0; m < 2; m++)
            #pragma unroll
            for (int n = 0; n < 4; n++){
                const int f = n*16 + lr;
                #pragma unroll
                for (int r = 0; r < 4; r++){
                    const int t = m*16 + lg*4 + r;
                    Hd[wv*2048 + t*64 + ((((f>>3) ^ (t & 7)) << 3) | (f & 7))] = f2bf(c[m][n][r]);
                }
            }
    };

    stage_coop(H1, ctx + (size_t)tokbase*64);
    __syncthreads();

    f32x4 c[2][4];

    // hg = gelu(ctx @ Wg1^T + bg1) -> H2
    gemm32(H1, wg1, bg1, c);
    #pragma unroll
    for (int m = 0; m < 2; m++)
        #pragma unroll
        for (int n = 0; n < 4; n++)
            #pragma unroll
            for (int r = 0; r < 4; r++) c[m][n][r] = gelu_exact(c[m][n][r]);
    storeH(H2, c);

    // src/dst gates
    {
        f32x4 c2[2];
        const float bv = (lr == 0) ? bsrc[0] : (lr == 1 ? bdst[0] : 0.f);
        #pragma unroll
        for (int m = 0; m < 2; m++){ f32x4 t = {bv,bv,bv,bv}; c2[m] = t; }
        #pragma unroll
        for (int kk = 0; kk < 2; kk++){
            short8 a[2];
            #pragma unroll
            for (int m = 0; m < 2; m++) a[m] = afrag(H1, m*16 + lr, kk*4 + lg);
            short8 w = {0,0,0,0,0,0,0,0};
            if (lr == 0) w = wfrag(wsrc, 0, kk*32 + lg*8);
            else if (lr == 1) w = wfrag(wdst, 0, kk*32 + lg*8);
            #pragma unroll
            for (int m = 0; m < 2; m++)
                c2[m] = __builtin_amdgcn_mfma_f32_16x16x32_bf16(a[m], w, c2[m], 0,0,0);
        }
        #pragma unroll
        for (int m = 0; m < 2; m++)
            #pragma unroll
            for (int r = 0; r < 4; r++){
                const int t = wtok + m*16 + lg*4 + r;
                const float v = sigmoidf_(c2[m][r]);
                if (lr == 0) sgate[t] = v;
                if (lr == 1) dgate[t] = v;
            }
    }

    // hs = gelu(ctx @ Ws1^T + bs1) -> H1 (wave-private slice, safe in place)
    gemm32(H1, ws1, bs1, c);
    #pragma unroll
    for (int m = 0; m < 2; m++)
        #pragma unroll
        for (int n = 0; n < 4; n++)
            #pragma unroll
            for (int r = 0; r < 4; r++) c[m][n][r] = gelu_exact(c[m][n][r]);
    storeH(H1, c);

    // gates = sigmoid(hg @ Wg2^T + bg2)
    float g0[2][4];
    {
        f32x4 c3[2];
        const float bv = (lr < 4) ? bg2[lr] : 0.f;
        #pragma unroll
        for (int m = 0; m < 2; m++){ f32x4 t = {bv,bv,bv,bv}; c3[m] = t; }
        #pragma unroll
        for (int kk = 0; kk < 2; kk++){
            short8 a[2];
            #pragma unroll
            for (int m = 0; m < 2; m++) a[m] = afrag(H2, m*16 + lr, kk*4 + lg);
            short8 w = {0,0,0,0,0,0,0,0};
            if (lr < 4) w = wfrag(wg2, lr, kk*32 + lg*8);
            #pragma unroll
            for (int m = 0; m < 2; m++)
                c3[m] = __builtin_amdgcn_mfma_f32_16x16x32_bf16(a[m], w, c3[m], 0,0,0);
        }
        #pragma unroll
        for (int m = 0; m < 2; m++)
            #pragma unroll
            for (int r = 0; r < 4; r++){
                const float v = sigmoidf_(c3[m][r]);
                if (lr < 4)
                    gates[(size_t)(tokbase + wtok + m*16 + lg*4 + r)*4 + lr] = v;
                g0[m][r] = __shfl(v, lane & 48, 64);
            }
    }

    // scale = sigmoid(hs @ Ws2^T + bs2) -> H1 -> coalesced store
    gemm32(H1, ws2, bs2, c);
    #pragma unroll
    for (int m = 0; m < 2; m++)
        #pragma unroll
        for (int n = 0; n < 4; n++)
            #pragma unroll
            for (int r = 0; r < 4; r++) c[m][n][r] = sigmoidf_(c[m][n][r]);
    storeH(H1, c);
    {
        #pragma unroll
        for (int it = 0; it < 4; it++){
            const int r2  = wtok + it*8 + (lane >> 3);
            const int sub = lane & 7;
            const short8 v = *(const short8*)&H1[r2*64 + ((sub ^ (r2 & 7)) << 3)];
            *(short8*)&scaleb[(size_t)(tokbase + r2)*64 + sub*8] = v;
        }
    }

    __syncthreads();
    stage_coop(H2, x + (size_t)tokbase*64);
    __syncthreads();

    // self = x @ Wself^T + bself; accb = bf16(g0 * self), repacked via H1
    gemm32(H2, wself, bself, c);
    #pragma unroll
    for (int m = 0; m < 2; m++)
        #pragma unroll
        for (int n = 0; n < 4; n++)
            #pragma unroll
            for (int r = 0; r < 4; r++) c[m][n][r] *= g0[m][r];
    storeH(H1, c);
    {
        #pragma unroll
        for (int it = 0; it < 4; it++){
            const int r2  = wtok + it*8 + (lane >> 3);
            const int sub = lane & 7;
            const short8 v = *(const short8*)&H1[r2*64 + ((sub ^ (r2 & 7)) << 3)];
            *(short8*)&accb[(size_t)(tokbase + r2)*64 + sub*8] = v;
        }
    }

    // coalesced f-major transposed outputs
    {
        const int tok  = tid & 127;
        const int fbh  = tid >> 7;            // 0 or 1
        const float dg = dgate[tok], sg = sgate[tok];
        const size_t ob = (size_t)bt*65536 + n0 + tok;
        #pragma unroll
        for (int q = 0; q < 4; q++){
            const int fb = fbh*4 + q;
            const short8 v = *(const short8*)&H2[tok*64 + ((fb ^ (tok & 7)) << 3)];
            #pragma unroll
            for (int j = 0; j < 8; j++){
                const u16 raw = (u16)v[j];
                const float xv = b2f(raw);
                const size_t o = ob + (size_t)(fb*8 + j)*1024;
                xTp[o] = raw;
                xTd[o] = f2bf(xv * dg);
                xTs[o] = f2bf(xv * sg);
            }
        }
    }
}

// ---------------------------------------------------------------------------
// MFMA diffusion GEMM + fused linear/gate epilogue.
//  WRITE_TMP: also write y (transposed bf16, coalesced) for the next step.
//  !FINAL: gated E staged bf16 in LDS, then coalesced short8 RMW of accb.
//  FINAL: scale*gelu+residual+layernorm -> out (f32), reads accb.
// Weights read direct from plain-bf16 wbf (L1-hot, 8 KB).
// ---------------------------------------------------------------------------
template<bool WRITE_TMP, bool FINAL>
__global__ __launch_bounds__(256, 2) void k_diffmm(
    const u16* __restrict__ adj,  const u16* __restrict__ srcT,
    const u16* __restrict__ Wbf,  const float* __restrict__ bias,
    const float* __restrict__ gates, const int branch,
    u16* __restrict__ accb, u16* __restrict__ tmpT,
    const float* __restrict__ x, const u16* __restrict__ scaleb,
    const float* __restrict__ gamma, const float* __restrict__ beta,
    float* __restrict__ out)
{
    __shared__ u16 sA[2][256*64];
    __shared__ u16 sB[2][64*64];

    const int tid = threadIdx.x;
    const int fb_ = blockIdx.x;
    const int s_  = (fb_ & 7) * 192 + (fb_ >> 3);
    const int bt  = s_ >> 2;
    const int n0  = (s_ & 3) * 256;
    const int wv  = tid >> 6, lane = tid & 63;
    const int lr  = lane & 15, lg = lane >> 4;
    const int wrow0 = wv * 64;

    const u16* asrc = adj  + (size_t)n0 * 1024;
    const u16* bsrc = srcT + (size_t)bt * 65536;

    auto stage = [&](int buf, int kt){
        const int m0 = kt * 64;
        #pragma unroll
        for (int i = 0; i < 8; i++){
            const int s = i*256 + tid;
            const int row = s >> 3, kbp = s & 7;
            const int kb = kbp ^ (row & 7);
            GLLDS(asrc + (size_t)row*1024 + m0 + kb*8, &sA[buf][s*8]);
        }
        #pragma unroll
        for (int i = 0; i < 2; i++){
            const int s = i*256 + tid;
            const int row = s >> 3, kbp = s & 7;
            const int kb = kbp ^ (row & 7);
            GLLDS(bsrc + (size_t)row*1024 + m0 + kb*8, &sB[buf][s*8]);
        }
    };

    const f32x4 z4 = {0.f, 0.f, 0.f, 0.f};
    f32x4 c[4][4];
    #pragma unroll
    for (int m = 0; m < 4; m++)
        #pragma unroll
        for (int n = 0; n < 4; n++) c[m][n] = z4;

    stage(0, 0);
    asm volatile("s_waitcnt vmcnt(0)" ::: "memory");
    __syncthreads();

    int cur = 0;
    for (int kt = 0; kt < 16; kt++){
        if (kt < 15) stage(cur ^ 1, kt + 1);
        const u16* A = sA[cur];
        const u16* B = sB[cur];
        short8 af[2][4], bfr[2][4];
        #pragma unroll
        for (int kk = 0; kk < 2; kk++){
            const int kb = lg + kk*4;
            #pragma unroll
            for (int m = 0; m < 4; m++){
                const int row = wrow0 + m*16 + lr;
                af[kk][m] = *(const short8*)&A[row*64 + ((kb ^ (row & 7)) << 3)];
            }
            #pragma unroll
            for (int n = 0; n < 4; n++){
                const int fr = n*16 + lr;
                bfr[kk][n] = *(const short8*)&B[fr*64 + ((kb ^ (fr & 7)) << 3)];
            }
        }
        #pragma unroll
        for (int kk = 0; kk < 2; kk++)
            #pragma unroll
            for (int m = 0; m < 4; m++)
                #pragma unroll
                for (int n = 0; n < 4; n++)
                    c[m][n] = __builtin_amdgcn_mfma_f32_16x16x32_bf16(
                        af[kk][m], bfr[kk][n], c[m][n], 0, 0, 0);
        asm volatile("s_waitcnt vmcnt(0)" ::: "memory");
        __syncthreads();
        cur ^= 1;
    }

    // stash yT (bf16, swizzled) into sA[0]; sA[1] becomes the E buffer
    u16* yT = &sA[0][0];
    u16* eL = &sA[1][0];
    #pragma unroll
    for (int m = 0; m < 4; m++)
        #pragma unroll
        for (int n = 0; n < 4; n++){
            const int f = n*16 + lr;
            #pragma unroll
            for (int r = 0; r < 4; r++){
                const int row = wrow0 + m*16 + lg*4 + r;
                yT[row*64 + (((f >> 3) ^ (row & 7)) << 3) + (f & 7)] = f2bf(c[m][n][r]);
            }
        }
    __syncthreads();

    // coalesced tmp write: thread tid owns node-row tid (reads all-wave yT)
    if (WRITE_TMP){
        const size_t ob = (size_t)bt*65536 + n0 + tid;
        #pragma unroll
        for (int fbk = 0; fbk < 8; fbk++){
            const short8 v = *(const short8*)&yT[tid*64 + ((fbk ^ (tid & 7)) << 3)];
            #pragma unroll
            for (int j = 0; j < 8; j++)
                tmpT[ob + (size_t)(fbk*8 + j)*1024] = (u16)v[j];
        }
    }

    // lin = y @ W^T via MFMA (K = 64); W fragments direct from global bf16
    f32x4 lin[4][4];
    #pragma unroll
    for (int m = 0; m < 4; m++)
        #pragma unroll
        for (int n = 0; n < 4; n++) lin[m][n] = z4;
    #pragma unroll
    for (int kk = 0; kk < 2; kk++){
        const int kb = lg + kk*4;
        short8 ya[4], wb[4];
        #pragma unroll
        for (int m = 0; m < 4; m++){
            const int row = wrow0 + m*16 + lr;
            ya[m] = *(const short8*)&yT[row*64 + ((kb ^ (row & 7)) << 3)];
        }
        #pragma unroll
        for (int n = 0; n < 4; n++)
            wb[n] = *(const short8*)&Wbf[(n*16 + lr)*64 + kb*8];
        #pragma unroll
        for (int m = 0; m < 4; m++)
            #pragma unroll
            for (int n = 0; n < 4; n++)
                lin[m][n] = __builtin_amdgcn_mfma_f32_16x16x32_bf16(
                    ya[m], wb[n], lin[m][n], 0, 0, 0);
    }

    if constexpr (!FINAL){
        // stage gated E (bf16, swizzled) into eL, then coalesced accb RMW
        #pragma unroll
        for (int m = 0; m < 4; m++){
            float g[4];
            #pragma unroll
            for (int r = 0; r < 4; r++){
                const int node = n0 + wrow0 + m*16 + lg*4 + r;
                g[r] = gates[((size_t)bt*1024 + node)*4 + branch];
            }
            #pragma unroll
            for (int n = 0; n < 4; n++){
                const int f = n*16 + lr;
                const float bv = bias[f];
                #pragma unroll
                for (int r = 0; r < 4; r++){
                    const int row = wrow0 + m*16 + lg*4 + r;
                    eL[row*64 + (((f >> 3) ^ (row & 7)) << 3) + (f & 7)]
                        = f2bf(g[r] * (lin[m][n][r] + bv));
                }
            }
        }
        __syncthreads();
        const size_t tokb = ((size_t)bt*1024 + n0 + tid)*64;
        #pragma unroll
        for (int fbk = 0; fbk < 8; fbk++){
            const short8 e = *(const short8*)&eL[tid*64 + ((fbk ^ (tid & 7)) << 3)];
            const short8 a = *(const short8*)&accb[tokb + fbk*8];
            short8 o;
            #pragma unroll
            for (int j = 0; j < 8; j++)
                o[j] = (short)f2bf(b2f((u16)a[j]) + b2f((u16)e[j]));
            *(short8*)&accb[tokb + fbk*8] = o;
        }
    } else {
        // fused final: mixed=(accb+g*(lin+b))*scale; h=x+gelu(mixed); LN -> out
        #pragma unroll
        for (int m = 0; m < 4; m++){
            #pragma unroll
            for (int r = 0; r < 4; r++){
                const int node = n0 + wrow0 + m*16 + lg*4 + r;
                const size_t tok = (size_t)bt*1024 + node;
                const float g = gates[tok*4 + branch];
                float h[4];
                #pragma unroll
                for (int n = 0; n < 4; n++){
                    const int f = n*16 + lr;
                    const float a = b2f(accb[tok*64 + f]) + g * (lin[m][n][r] + bias[f]);
                    const float mixed = a * b2f(scaleb[tok*64 + f]);
                    h[n] = x[tok*64 + f] + gelu_exact(mixed);
                }
                float s = h[0] + h[1] + h[2] + h[3];
                #pragma unroll
                for (int o = 8; o > 0; o >>= 1) s += __shfl_xor(s, o, 64);
                const float mu = s * (1.0f/64.0f);
                float vs = 0.f;
                #pragma unroll
                for (int n = 0; n < 4; n++){ const float d = h[n] - mu; vs += d*d; }
                #pragma unroll
                for (int o = 8; o > 0; o >>= 1) vs += __shfl_xor(vs, o, 64);
                const float inv = rsqrtf(vs * (1.0f/64.0f) + LN_EPS);
                #pragma unroll
                for (int n = 0; n < 4; n++){
                    const int f = n*16 + lr;
                    out[tok*64 + f] = (h[n] - mu) * inv * gamma[f] + beta[f];
                }
            }
        }
    }
}

// ---------------------------------------------------------------------------
extern "C" void kernel_launch(void* const* d_in, const int* in_sizes, int n_in,
                              void* d_out, int out_size, void* d_ws, size_t ws_size,
                              hipStream_t stream)
{
    const float* x      = (const float*)d_in[0];
    const float* a_fwd  = (const float*)d_in[1];
    const float* ctx    = (const float*)d_in[2];
    const float* W_self = (const float*)d_in[3];
    const float* b_self = (const float*)d_in[4];
    const float* W_fwd  = (const float*)d_in[5];
    const float* b_fwd  = (const float*)d_in[6];
    const float* W_bwd  = (const float*)d_in[7];
    const float* b_bwd  = (const float*)d_in[8];
    const float* W_adp  = (const float*)d_in[9];
    const float* b_adp  = (const float*)d_in[10];
    const float* Wg1    = (const float*)d_in[11];
    const float* bg1    = (const float*)d_in[12];
    const float* Wg2    = (const float*)d_in[13];
    const float* bg2    = (const float*)d_in[14];
    const float* Ws1    = (const float*)d_in[15];
    const float* bs1    = (const float*)d_in[16];
    const float* Ws2    = (const float*)d_in[17];
    const float* bs2    = (const float*)d_in[18];
    const float* W_src  = (const float*)d_in[19];
    const float* b_src  = (const float*)d_in[20];
    const float* W_dst  = (const float*)d_in[21];
    const float* b_dst  = (const float*)d_in[22];
    const float* emb_src= (const float*)d_in[23];
    const float* emb_dst= (const float*)d_in[24];
    const float* gamma  = (const float*)d_in[25];
    const float* beta   = (const float*)d_in[26];

    float* out = (float*)d_out;
    char*  w   = (char*)d_ws;
    const size_t MB48 = 50331648ull;
    u16* afwd_bf = (u16*)(w);
    u16* abwd_bf = (u16*)(w + 2097152ull);
    u16* aadp_bf = (u16*)(w + 4194304ull);
    u16* xTp     = (u16*)(w + 6291456ull);
    u16* xTd     = (u16*)(w + 6291456ull + 1*MB48);
    u16* xTs     = (u16*)(w + 6291456ull + 2*MB48);
    u16* tmpT    = (u16*)(w + 6291456ull + 3*MB48);
    u16* scaleb  = (u16*)(w + 6291456ull + 4*MB48);
    u16* accb    = (u16*)(w + 6291456ull + 5*MB48);
    float* gates = (float*)(w + 6291456ull + 6*MB48);
    u16* wbf     = (u16*)(w + 6291456ull + 6*MB48 + 8388608ull);

    k_prep  <<<162, 256, 0, stream>>>(Wg1, Ws1, Ws2, W_self, Wg2, W_src, W_dst,
                                      W_fwd, W_bwd, W_adp, wbf);
    k_adp   <<<1024, 256, 0, stream>>>(emb_src, emb_dst, aadp_bf);
    k_cvtbwd<<<dim3(32,32), 256, 0, stream>>>(a_fwd, afwd_bf, abwd_bf);
    k_gating<<<3072, 256, 0, stream>>>(x, ctx,
                                       wbf + 0,     bg1,  wbf + 40960, bg2,
                                       wbf + 4096,  bs1,  wbf + 8192,  bs2,
                                       wbf + 41216, b_src, wbf + 41280, b_dst,
                                       wbf + 12288, b_self,
                                       gates, scaleb, accb, xTp, xTd, xTs);

    k_diffmm<true ,false><<<1536,256,0,stream>>>(afwd_bf, xTd,  wbf+16384, b_fwd,
                                                 gates, 1, accb, tmpT,
                                                 nullptr, nullptr, nullptr, nullptr, nullptr);
    k_diffmm<false,false><<<1536,256,0,stream>>>(afwd_bf, tmpT, wbf+20480, b_fwd+64,
                                                 gates, 1, accb, nullptr,
                                                 nullptr, nullptr, nullptr, nullptr, nullptr);
    k_diffmm<true ,false><<<1536,256,0,stream>>>(abwd_bf, xTs,  wbf+24576, b_bwd,
                                                 gates, 2, accb, tmpT,
                                                 nullptr, nullptr, nullptr, nullptr, nullptr);
    k_diffmm<false,false><<<1536,256,0,stream>>>(abwd_bf, tmpT, wbf+28672, b_bwd+64,
                                                 gates, 2, accb, nullptr,
                                                 nullptr, nullptr, nullptr, nullptr, nullptr);
    k_diffmm<true ,false><<<1536,256,0,stream>>>(aadp_bf, xTp,  wbf+32768, b_adp,
                                                 gates, 3, accb, tmpT,
                                                 nullptr, nullptr, nullptr, nullptr, nullptr);
    k_diffmm<false,true ><<<1536,256,0,stream>>>(aadp_bf, tmpT, wbf+36864, b_adp+64,
                                                 gates, 3, accb, nullptr,
                                                 x, scaleb, gamma, beta, out);
}

// Round 9
// 869.390 us; speedup vs baseline: 1.6855x; 1.1342x over previous
//
#include <hip/hip_runtime.h>
#include <math.h>

typedef unsigned short u16;
typedef short short8 __attribute__((ext_vector_type(8)));
typedef float f32x4 __attribute__((ext_vector_type(4)));

#define LN_EPS 1e-5f

__device__ __forceinline__ float gelu_exact(float x){
    return 0.5f * x * (1.0f + erff(x * 0.70710678118654752f));
}
__device__ __forceinline__ float sigmoidf_(float x){
    return 1.0f / (1.0f + __expf(-x));
}
__device__ __forceinline__ u16 f2bf(float f){            // RTNE f32->bf16
    unsigned u = __float_as_uint(f);
    u += 0x7fffu + ((u >> 16) & 1u);
    return (u16)(u >> 16);
}
__device__ __forceinline__ float b2f(u16 u){
    return __uint_as_float(((unsigned)u) << 16);
}

#define GLLDS(gp, lp) __builtin_amdgcn_global_load_lds( \
    (const __attribute__((address_space(1))) unsigned int*)(const void*)(gp), \
    (__attribute__((address_space(3))) unsigned int*)(void*)(lp), 16, 0, 0)

// ---------------------------------------------------------------------------
// One-time: convert all weight matrices to plain bf16 into wbf.
// Layout (u16 offsets): 0 Wg1 | 4096 Ws1 | 8192 Ws2 | 12288 Wself |
// 16384 Wfwd(2x) | 24576 Wbwd(2x) | 32768 Wadp(2x) | 40960 Wg2 |
// 41216 Wsrc | 41280 Wdst   (total 41344)
// ---------------------------------------------------------------------------
__global__ __launch_bounds__(256) void k_prep(
    const float* __restrict__ Wg1, const float* __restrict__ Ws1,
    const float* __restrict__ Ws2, const float* __restrict__ Wself,
    const float* __restrict__ Wg2, const float* __restrict__ Wsrc,
    const float* __restrict__ Wdst, const float* __restrict__ Wfwd,
    const float* __restrict__ Wbwd, const float* __restrict__ Wadp,
    u16* __restrict__ wbf)
{
    const int i = blockIdx.x*256 + threadIdx.x;
    if (i >= 41344) return;
    const float* src; int off;
    if      (i < 4096)  { src = Wg1;  off = 0; }
    else if (i < 8192)  { src = Ws1;  off = 4096; }
    else if (i < 12288) { src = Ws2;  off = 8192; }
    else if (i < 16384) { src = Wself;off = 12288; }
    else if (i < 24576) { src = Wfwd; off = 16384; }
    else if (i < 32768) { src = Wbwd; off = 24576; }
    else if (i < 40960) { src = Wadp; off = 32768; }
    else if (i < 41216) { src = Wg2;  off = 40960; }
    else if (i < 41280) { src = Wsrc; off = 41216; }
    else                { src = Wdst; off = 41280; }
    wbf[i] = f2bf(src[i - off]);
}

// ---------------------------------------------------------------------------
// a_adp = softmax(relu(emb_src @ emb_dst^T)) -> bf16 [1024][1024]
// ---------------------------------------------------------------------------
__global__ __launch_bounds__(256) void k_adp(const float* __restrict__ es,
                                             const float* __restrict__ ed,
                                             u16* __restrict__ aadp){
    __shared__ float srow[1024];
    __shared__ float s_es[16];
    __shared__ float sredm[4];
    __shared__ float sreds[4];
    const int n   = blockIdx.x;
    const int tid = threadIdx.x;
    const int wid = tid >> 6, lane = tid & 63;
    if (tid < 16) s_es[tid] = es[n*16 + tid];
    __syncthreads();
    float lmax = 0.0f;
    for (int m = tid; m < 1024; m += 256){
        const float* edm = ed + m*16;
        float z = 0.f;
        #pragma unroll
        for (int r = 0; r < 16; r++) z = fmaf(s_es[r], edm[r], z);
        z = fmaxf(z, 0.0f);
        srow[m] = z;
        lmax = fmaxf(lmax, z);
    }
    #pragma unroll
    for (int o = 32; o > 0; o >>= 1) lmax = fmaxf(lmax, __shfl_xor(lmax, o, 64));
    if (lane == 0) sredm[wid] = lmax;
    __syncthreads();
    const float tmax = fmaxf(fmaxf(sredm[0], sredm[1]), fmaxf(sredm[2], sredm[3]));
    float lsum = 0.f;
    for (int m = tid; m < 1024; m += 256){
        float e = expf(srow[m] - tmax);
        srow[m] = e;
        lsum += e;
    }
    #pragma unroll
    for (int o = 32; o > 0; o >>= 1) lsum += __shfl_xor(lsum, o, 64);
    if (lane == 0) sreds[wid] = lsum;
    __syncthreads();
    const float inv = 1.0f / (sreds[0] + sreds[1] + sreds[2] + sreds[3]);
    for (int m = tid; m < 1024; m += 256) aadp[(size_t)n*1024 + m] = f2bf(srow[m] * inv);
}

// ---------------------------------------------------------------------------
// afwd = bf16(a_fwd);  abwd[n][m] = bf16(a_fwd[m][n])   (one pass)
// ---------------------------------------------------------------------------
__global__ __launch_bounds__(256) void k_cvtbwd(const float* __restrict__ a,
                                                u16* __restrict__ afwd,
                                                u16* __restrict__ abwd){
    __shared__ float t[32][33];
    const int bx = blockIdx.x*32, by = blockIdx.y*32;
    const int tx = threadIdx.x & 31, ty = threadIdx.x >> 5;
    #pragma unroll
    for (int i = 0; i < 4; i++){
        const float v = a[(size_t)(by + ty + 8*i)*1024 + bx + tx];
        t[ty + 8*i][tx] = v;
        afwd[(size_t)(by + ty + 8*i)*1024 + bx + tx] = f2bf(v);
    }
    __syncthreads();
    #pragma unroll
    for (int i = 0; i < 4; i++)
        at_:
        abwd[(size_t)(bx + ty + 8*i)*1024 + by + tx] = f2bf(t[tx][ty + 8*i]);
}

// ---------------------------------------------------------------------------
// MFMA gating kernel — 128 tokens/block; bf16 weights read direct from wbf.
// Outputs: gates(f32), scaleb(bf16), accb = bf16(g0*self), xTp/xTd/xTs.
// ---------------------------------------------------------------------------
__global__ __launch_bounds__(256, 4) void k_gating(
    const float* __restrict__ x,    const float* __restrict__ ctx,
    const u16* __restrict__ wg1,  const float* __restrict__ bg1,
    const u16* __restrict__ wg2,  const float* __restrict__ bg2,
    const u16* __restrict__ ws1,  const float* __restrict__ bs1,
    const u16* __restrict__ ws2,  const float* __restrict__ bs2,
    const u16* __restrict__ wsrc, const float* __restrict__ bsrc,
    const u16* __restrict__ wdst, const float* __restrict__ bdst,
    const u16* __restrict__ wself,const float* __restrict__ bself,
    float* __restrict__ gates, u16* __restrict__ scaleb,
    u16* __restrict__ accb,
    u16* __restrict__ xTp, u16* __restrict__ xTd, u16* __restrict__ xTs)
{
    __shared__ u16 H1[8192];      // 16 KB
    __shared__ u16 H2[8192];      // 16 KB
    __shared__ float sgate[128], dgate[128];

    const int tid  = threadIdx.x;
    const int wv   = tid >> 6, lane = tid & 63;
    const int lr   = lane & 15, lg = lane >> 4;
    const int wtok = wv * 32;
    const int tokbase = blockIdx.x * 128;
    const int bt = blockIdx.x >> 3;
    const int n0 = (blockIdx.x & 7) * 128;

    auto stage_coop = [&](u16* H, const float* g){
        #pragma unroll
        for (int i = 0; i < 8; i++){
            const int fid = i*256 + tid;
            const int t = fid >> 4, q = fid & 15;
            const float4 v = *(const float4*)&g[(size_t)t*64 + q*4];
            ushort4 s;
            s.x = f2bf(v.x); s.y = f2bf(v.y); s.z = f2bf(v.z); s.w = f2bf(v.w);
            *(ushort4*)&H[t*64 + ((((q>>1) ^ (t & 7)) << 3) | ((q & 1)*4))] = s;
        }
    };
    auto afrag = [&](const u16* H, int row, int kb)->short8{
        return *(const short8*)&H[wv*2048 + row*64 + ((kb ^ (row & 7)) << 3)];
    };
    auto wfrag = [&](const u16* W, int o, int kb8)->short8{
        return *(const short8*)&W[o*64 + kb8];
    };
    auto gemm32 = [&](const u16* Hs, const u16* W, const float* bias, f32x4 (&c)[2][4]){
        #pragma unroll
        for (int n = 0; n < 4; n++){
            const float bv = bias[n*16 + lr];
            #pragma unroll
            for (int m = 0; m < 2; m++){ f32x4 t = {bv,bv,bv,bv}; c[m][n] = t; }
        }
        #pragma unroll
        for (int kk = 0; kk < 2; kk++){
            short8 a[2];
            #pragma unroll
            for (int m = 0; m < 2; m++) a[m] = afrag(Hs, m*16 + lr, kk*4 + lg);
            #pragma unroll
            for (int n = 0; n < 4; n++){
                const short8 w = wfrag(W, n*16 + lr, kk*32 + lg*8);
                #pragma unroll
                for (int m = 0; m < 2; m++)
                    c[m][n] = __builtin_amdgcn_mfma_f32_16x16x32_bf16(a[m], w, c[m][n], 0,0,0);
            }
        }
    };
    auto storeH = [&](u16* Hd, f32x4 (&c)[2][4]){
        #pragma unroll
        for (int m = 0; m < 2; m++)
            #pragma unroll
            for (int n = 0; n < 4; n++){
                const int f = n*16 + lr;
                #pragma unroll
                for (int r = 0; r < 4; r++){
                    const int t = m*16 + lg*4 + r;
                    Hd[wv*2048 + t*64 + ((((f>>3) ^ (t & 7)) << 3) | (f & 7))] = f2bf(c[m][n][r]);
                }
            }
    };

    stage_coop(H1, ctx + (size_t)tokbase*64);
    __syncthreads();

    f32x4 c[2][4];

    // hg = gelu(ctx @ Wg1^T + bg1) -> H2
    gemm32(H1, wg1, bg1, c);
    #pragma unroll
    for (int m = 0; m < 2; m++)
        #pragma unroll
        for (int n = 0; n < 4; n++)
            #pragma unroll
            for (int r = 0; r < 4; r++) c[m][n][r] = gelu_exact(c[m][n][r]);
    storeH(H2, c);

    // src/dst gates
    {
        f32x4 c2[2];
        const float bv = (lr == 0) ? bsrc[0] : (lr == 1 ? bdst[0] : 0.f);
        #pragma unroll
        for (int m = 0; m < 2; m++){ f32x4 t = {bv,bv,bv,bv}; c2[m] = t; }
        #pragma unroll
        for (int kk = 0; kk < 2; kk++){
            short8 a[2];
            #pragma unroll
            for (int m = 0; m < 2; m++) a[m] = afrag(H1, m*16 + lr, kk*4 + lg);
            short8 w = {0,0,0,0,0,0,0,0};
            if (lr == 0) w = wfrag(wsrc, 0, kk*32 + lg*8);
            else if (lr == 1) w = wfrag(wdst, 0, kk*32 + lg*8);
            #pragma unroll
            for (int m = 0; m < 2; m++)
                c2[m] = __builtin_amdgcn_mfma_f32_16x16x32_bf16(a[m], w, c2[m], 0,0,0);
        }
        #pragma unroll
        for (int m = 0; m < 2; m++)
            #pragma unroll
            for (int r = 0; r < 4; r++){
                const int t = wtok + m*16 + lg*4 + r;
                const float v = sigmoidf_(c2[m][r]);
                if (lr == 0) sgate[t] = v;
                if (lr == 1) dgate[t] = v;
            }
    }

    // hs = gelu(ctx @ Ws1^T + bs1) -> H1 (wave-private slice, safe in place)
    gemm32(H1, ws1, bs1, c);
    #pragma unroll
    for (int m = 0; m < 2; m++)
        #pragma unroll
        for (int n = 0; n < 4; n++)
            #pragma unroll
            for (int r = 0; r < 4; r++) c[m][n][r] = gelu_exact(c[m][n][r]);
    storeH(H1, c);

    // gates = sigmoid(hg @ Wg2^T + bg2)
    float g0[2][4];
    {
        f32x4 c3[2];
        const float bv = (lr < 4) ? bg2[lr] : 0.f;
        #pragma unroll
        for (int m = 0; m < 2; m++){ f32x4 t = {bv,bv,bv,bv}; c3[m] = t; }
        #pragma unroll
        for (int kk = 0; kk < 2; kk++){
            short8 a[2];
            #pragma unroll
            for (int m = 0; m < 2; m++) a[m] = afrag(H2, m*16 + lr, kk*4 + lg);
            short8 w = {0,0,0,0,0,0,0,0};
            if (lr < 4) w = wfrag(wg2, lr, kk*32 + lg*8);
            #pragma unroll
            for (int m = 0; m < 2; m++)
                c3[m] = __builtin_amdgcn_mfma_f32_16x16x32_bf16(a[m], w, c3[m], 0,0,0);
        }
        #pragma unroll
        for (int m = 0; m < 2; m++)
            #pragma unroll
            for (int r = 0; r < 4; r++){
                const float v = sigmoidf_(c3[m][r]);
                if (lr < 4)
                    gates[(size_t)(tokbase + wtok + m*16 + lg*4 + r)*4 + lr] = v;
                g0[m][r] = __shfl(v, lane & 48, 64);
            }
    }

    // scale = sigmoid(hs @ Ws2^T + bs2) -> H1 -> coalesced store
    gemm32(H1, ws2, bs2, c);
    #pragma unroll
    for (int m = 0; m < 2; m++)
        #pragma unroll
        for (int n = 0; n < 4; n++)
            #pragma unroll
            for (int r = 0; r < 4; r++) c[m][n][r] = sigmoidf_(c[m][n][r]);
    storeH(H1, c);
    {
        #pragma unroll
        for (int it = 0; it < 4; it++){
            const int r2  = wtok + it*8 + (lane >> 3);
            const int sub = lane & 7;
            const short8 v = *(const short8*)&H1[r2*64 + ((sub ^ (r2 & 7)) << 3)];
            *(short8*)&scaleb[(size_t)(tokbase + r2)*64 + sub*8] = v;
        }
    }

    __syncthreads();
    stage_coop(H2, x + (size_t)tokbase*64);
    __syncthreads();

    // self = x @ Wself^T + bself; accb = bf16(g0 * self), repacked via H1
    gemm32(H2, wself, bself, c);
    #pragma unroll
    for (int m = 0; m < 2; m++)
        #pragma unroll
        for (int n = 0; n < 4; n++)
            #pragma unroll
            for (int r = 0; r < 4; r++) c[m][n][r] *= g0[m][r];
    storeH(H1, c);
    {
        #pragma unroll
        for (int it = 0; it < 4; it++){
            const int r2  = wtok + it*8 + (lane >> 3);
            const int sub = lane & 7;
            const short8 v = *(const short8*)&H1[r2*64 + ((sub ^ (r2 & 7)) << 3)];
            *(short8*)&accb[(size_t)(tokbase + r2)*64 + sub*8] = v;
        }
    }

    // coalesced f-major transposed outputs
    {
        const int tok  = tid & 127;
        const int fbh  = tid >> 7;            // 0 or 1
        const float dg = dgate[tok], sg = sgate[tok];
        const size_t ob = (size_t)bt*65536 + n0 + tok;
        #pragma unroll
        for (int q = 0; q < 4; q++){
            const int fb = fbh*4 + q;
            const short8 v = *(const short8*)&H2[tok*64 + ((fb ^ (tok & 7)) << 3)];
            #pragma unroll
            for (int j = 0; j < 8; j++){
                const u16 raw = (u16)v[j];
                const float xv = b2f(raw);
                const size_t o = ob + (size_t)(fb*8 + j)*1024;
                xTp[o] = raw;
                xTd[o] = f2bf(xv * dg);
                xTs[o] = f2bf(xv * sg);
            }
        }
    }
}

// ---------------------------------------------------------------------------
// MFMA diffusion GEMM + fused linear/gate epilogue.
// BM=128 (was 256): LDS 48 KB -> 3 blocks/CU (latency-bound fix), grid 3072.
//  WRITE_TMP: also write y (transposed bf16, coalesced) for the next step.
//  !FINAL: gated E staged bf16 in LDS, then coalesced short8 RMW of accb.
//  FINAL: scale*gelu+residual+layernorm -> out (f32), reads accb.
// XCD-aware remap keeps one bt's 8 n-tiles on one XCD (srcT L2 reuse).
// ---------------------------------------------------------------------------
template<bool WRITE_TMP, bool FINAL>
__global__ __launch_bounds__(256, 3) void k_diffmm(
    const u16* __restrict__ adj,  const u16* __restrict__ srcT,
    const u16* __restrict__ Wbf,  const float* __restrict__ bias,
    const float* __restrict__ gates, const int branch,
    u16* __restrict__ accb, u16* __restrict__ tmpT,
    const float* __restrict__ x, const u16* __restrict__ scaleb,
    const float* __restrict__ gamma, const float* __restrict__ beta,
    float* __restrict__ out)
{
    __shared__ u16 sA[2][128*64];   // 2 x 16 KB
    __shared__ u16 sB[2][64*64];    // 2 x 8 KB

    const int tid = threadIdx.x;
    const int fb_ = blockIdx.x;                 // 0..3071
    const int s_  = (fb_ & 7) * 384 + (fb_ >> 3);
    const int bt  = s_ >> 3;
    const int n0  = (s_ & 7) * 128;
    const int wv  = tid >> 6, lane = tid & 63;
    const int lr  = lane & 15, lg = lane >> 4;
    const int wrow0 = wv * 32;

    const u16* asrc = adj  + (size_t)n0 * 1024;
    const u16* bsrc = srcT + (size_t)bt * 65536;

    auto stage = [&](int buf, int kt){
        const int m0 = kt * 64;
        #pragma unroll
        for (int i = 0; i < 4; i++){
            const int s = i*256 + tid;
            const int row = s >> 3, kbp = s & 7;
            const int kb = kbp ^ (row & 7);
            GLLDS(asrc + (size_t)row*1024 + m0 + kb*8, &sA[buf][s*8]);
        }
        #pragma unroll
        for (int i = 0; i < 2; i++){
            const int s = i*256 + tid;
            const int row = s >> 3, kbp = s & 7;
            const int kb = kbp ^ (row & 7);
            GLLDS(bsrc + (size_t)row*1024 + m0 + kb*8, &sB[buf][s*8]);
        }
    };

    const f32x4 z4 = {0.f, 0.f, 0.f, 0.f};
    f32x4 c[2][4];
    #pragma unroll
    for (int m = 0; m < 2; m++)
        #pragma unroll
        for (int n = 0; n < 4; n++) c[m][n] = z4;

    stage(0, 0);
    asm volatile("s_waitcnt vmcnt(0)" ::: "memory");
    __syncthreads();

    int cur = 0;
    for (int kt = 0; kt < 16; kt++){
        if (kt < 15) stage(cur ^ 1, kt + 1);
        const u16* A = sA[cur];
        const u16* B = sB[cur];
        short8 af[2][2], bfr[2][4];
        #pragma unroll
        for (int kk = 0; kk < 2; kk++){
            const int kb = lg + kk*4;
            #pragma unroll
            for (int m = 0; m < 2; m++){
                const int row = wrow0 + m*16 + lr;
                af[kk][m] = *(const short8*)&A[row*64 + ((kb ^ (row & 7)) << 3)];
            }
            #pragma unroll
            for (int n = 0; n < 4; n++){
                const int fr = n*16 + lr;
                bfr[kk][n] = *(const short8*)&B[fr*64 + ((kb ^ (fr & 7)) << 3)];
            }
        }
        #pragma unroll
        for (int kk = 0; kk < 2; kk++)
            #pragma unroll
            for (int m = 0; m < 2; m++)
                #pragma unroll
                for (int n = 0; n < 4; n++)
                    c[m][n] = __builtin_amdgcn_mfma_f32_16x16x32_bf16(
                        af[kk][m], bfr[kk][n], c[m][n], 0, 0, 0);
        asm volatile("s_waitcnt vmcnt(0)" ::: "memory");
        __syncthreads();
        cur ^= 1;
    }

    // stash yT (bf16, swizzled) into sA[0]; sA[1] becomes the E buffer
    u16* yT = &sA[0][0];
    u16* eL = &sA[1][0];
    #pragma unroll
    for (int m = 0; m < 2; m++)
        #pragma unroll
        for (int n = 0; n < 4; n++){
            const int f = n*16 + lr;
            #pragma unroll
            for (int r = 0; r < 4; r++){
                const int row = wrow0 + m*16 + lg*4 + r;
                yT[row*64 + (((f >> 3) ^ (row & 7)) << 3) + (f & 7)] = f2bf(c[m][n][r]);
            }
        }
    __syncthreads();

    // coalesced tmp write: 2 threads per node-row (halves of the fb range)
    const int rowt = tid >> 1, half = tid & 1;
    if (WRITE_TMP){
        const size_t ob = (size_t)bt*65536 + n0 + rowt;
        #pragma unroll
        for (int q = 0; q < 4; q++){
            const int fbk = half*4 + q;
            const short8 v = *(const short8*)&yT[rowt*64 + ((fbk ^ (rowt & 7)) << 3)];
            #pragma unroll
            for (int j = 0; j < 8; j++)
                tmpT[ob + (size_t)(fbk*8 + j)*1024] = (u16)v[j];
        }
    }

    // lin = y @ W^T via MFMA (K = 64); W fragments direct from global bf16
    f32x4 lin[2][4];
    #pragma unroll
    for (int m = 0; m < 2; m++)
        #pragma unroll
        for (int n = 0; n < 4; n++) lin[m][n] = z4;
    #pragma unroll
    for (int kk = 0; kk < 2; kk++){
        const int kb = lg + kk*4;
        short8 ya[2], wb[4];
        #pragma unroll
        for (int m = 0; m < 2; m++){
            const int row = wrow0 + m*16 + lr;
            ya[m] = *(const short8*)&yT[row*64 + ((kb ^ (row & 7)) << 3)];
        }
        #pragma unroll
        for (int n = 0; n < 4; n++)
            wb[n] = *(const short8*)&Wbf[(n*16 + lr)*64 + kb*8];
        #pragma unroll
        for (int m = 0; m < 2; m++)
            #pragma unroll
            for (int n = 0; n < 4; n++)
                lin[m][n] = __builtin_amdgcn_mfma_f32_16x16x32_bf16(
                    ya[m], wb[n], lin[m][n], 0, 0, 0);
    }

    if constexpr (!FINAL){
        // stage gated E (bf16, swizzled) into eL, then coalesced accb RMW
        #pragma unroll
        for (int m = 0; m < 2; m++){
            float g[4];
            #pragma unroll
            for (int r = 0; r < 4; r++){
                const int node = n0 + wrow0 + m*16 + lg*4 + r;
                g[r] = gates[((size_t)bt*1024 + node)*4 + branch];
            }
            #pragma unroll
            for (int n = 0; n < 4; n++){
                const int f = n*16 + lr;
                const float bv = bias[f];
                #pragma unroll
                for (int r = 0; r < 4; r++){
                    const int row = wrow0 + m*16 + lg*4 + r;
                    eL[row*64 + (((f >> 3) ^ (row & 7)) << 3) + (f & 7)]
                        = f2bf(g[r] * (lin[m][n][r] + bv));
                }
            }
        }
        __syncthreads();
        const size_t tokb = ((size_t)bt*1024 + n0 + rowt)*64;
        #pragma unroll
        for (int q = 0; q < 4; q++){
            const int fbk = half*4 + q;
            const short8 e = *(const short8*)&eL[rowt*64 + ((fbk ^ (rowt & 7)) << 3)];
            const short8 a = *(const short8*)&accb[tokb + fbk*8];
            short8 o;
            #pragma unroll
            for (int j = 0; j < 8; j++)
                o[j] = (short)f2bf(b2f((u16)a[j]) + b2f((u16)e[j]));
            *(short8*)&accb[tokb + fbk*8] = o;
        }
    } else {
        // fused final: mixed=(accb+g*(lin+b))*scale; h=x+gelu(mixed); LN -> out
        #pragma unroll
        for (int m = 0; m < 2; m++){
            #pragma unroll
            for (int r = 0; r < 4; r++){
                const int node = n0 + wrow0 + m*16 + lg*4 + r;
                const size_t tok = (size_t)bt*1024 + node;
                const float g = gates[tok*4 + branch];
                float h[4];
                #pragma unroll
                for (int n = 0; n < 4; n++){
                    const int f = n*16 + lr;
                    const float a = b2f(accb[tok*64 + f]) + g * (lin[m][n][r] + bias[f]);
                    const float mixed = a * b2f(scaleb[tok*64 + f]);
                    h[n] = x[tok*64 + f] + gelu_exact(mixed);
                }
                float s = h[0] + h[1] + h[2] + h[3];
                #pragma unroll
                for (int o = 8; o > 0; o >>= 1) s += __shfl_xor(s, o, 64);
                const float mu = s * (1.0f/64.0f);
                float vs = 0.f;
                #pragma unroll
                for (int n = 0; n < 4; n++){ const float d = h[n] - mu; vs += d*d; }
                #pragma unroll
                for (int o = 8; o > 0; o >>= 1) vs += __shfl_xor(vs, o, 64);
                const float inv = rsqrtf(vs * (1.0f/64.0f) + LN_EPS);
                #pragma unroll
                for (int n = 0; n < 4; n++){
                    const int f = n*16 + lr;
                    out[tok*64 + f] = (h[n] - mu) * inv * gamma[f] + beta[f];
                }
            }
        }
    }
}

// ---------------------------------------------------------------------------
extern "C" void kernel_launch(void* const* d_in, const int* in_sizes, int n_in,
                              void* d_out, int out_size, void* d_ws, size_t ws_size,
                              hipStream_t stream)
{
    const float* x      = (const float*)d_in[0];
    const float* a_fwd  = (const float*)d_in[1];
    const float* ctx    = (const float*)d_in[2];
    const float* W_self = (const float*)d_in[3];
    const float* b_self = (const float*)d_in[4];
    const float* W_fwd  = (const float*)d_in[5];
    const float* b_fwd  = (const float*)d_in[6];
    const float* W_bwd  = (const float*)d_in[7];
    const float* b_bwd  = (const float*)d_in[8];
    const float* W_adp  = (const float*)d_in[9];
    const float* b_adp  = (const float*)d_in[10];
    const float* Wg1    = (const float*)d_in[11];
    const float* bg1    = (const float*)d_in[12];
    const float* Wg2    = (const float*)d_in[13];
    const float* bg2    = (const float*)d_in[14];
    const float* Ws1    = (const float*)d_in[15];
    const float* bs1    = (const float*)d_in[16];
    const float* Ws2    = (const float*)d_in[17];
    const float* bs2    = (const float*)d_in[18];
    const float* W_src  = (const float*)d_in[19];
    const float* b_src  = (const float*)d_in[20];
    const float* W_dst  = (const float*)d_in[21];
    const float* b_dst  = (const float*)d_in[22];
    const float* emb_src= (const float*)d_in[23];
    const float* emb_dst= (const float*)d_in[24];
    const float* gamma  = (const float*)d_in[25];
    const float* beta   = (const float*)d_in[26];

    float* out = (float*)d_out;
    char*  w   = (char*)d_ws;
    const size_t MB48 = 50331648ull;
    u16* afwd_bf = (u16*)(w);
    u16* abwd_bf = (u16*)(w + 2097152ull);
    u16* aadp_bf = (u16*)(w + 4194304ull);
    u16* xTp     = (u16*)(w + 6291456ull);
    u16* xTd     = (u16*)(w + 6291456ull + 1*MB48);
    u16* xTs     = (u16*)(w + 6291456ull + 2*MB48);
    u16* tmpT    = (u16*)(w + 6291456ull + 3*MB48);
    u16* scaleb  = (u16*)(w + 6291456ull + 4*MB48);
    u16* accb    = (u16*)(w + 6291456ull + 5*MB48);
    float* gates = (float*)(w + 6291456ull + 6*MB48);
    u16* wbf     = (u16*)(w + 6291456ull + 6*MB48 + 8388608ull);

    k_prep  <<<162, 256, 0, stream>>>(Wg1, Ws1, Ws2, W_self, Wg2, W_src, W_dst,
                                      W_fwd, W_bwd, W_adp, wbf);
    k_adp   <<<1024, 256, 0, stream>>>(emb_src, emb_dst, aadp_bf);
    k_cvtbwd<<<dim3(32,32), 256, 0, stream>>>(a_fwd, afwd_bf, abwd_bf);
    k_gating<<<3072, 256, 0, stream>>>(x, ctx,
                                       wbf + 0,     bg1,  wbf + 40960, bg2,
                                       wbf + 4096,  bs1,  wbf + 8192,  bs2,
                                       wbf + 41216, b_src, wbf + 41280, b_dst,
                                       wbf + 12288, b_self,
                                       gates, scaleb, accb, xTp, xTd, xTs);

    k_diffmm<true ,false><<<3072,256,0,stream>>>(afwd_bf, xTd,  wbf+16384, b_fwd,
                                                 gates, 1, accb, tmpT,
                                                 nullptr, nullptr, nullptr, nullptr, nullptr);
    k_diffmm<false,false><<<3072,256,0,stream>>>(afwd_bf, tmpT, wbf+20480, b_fwd+64,
                                                 gates, 1, accb, nullptr,
                                                 nullptr, nullptr, nullptr, nullptr, nullptr);
    k_diffmm<true ,false><<<3072,256,0,stream>>>(abwd_bf, xTs,  wbf+24576, b_bwd,
                                                 gates, 2, accb, tmpT,
                                                 nullptr, nullptr, nullptr, nullptr, nullptr);
    k_diffmm<false,false><<<3072,256,0,stream>>>(abwd_bf, tmpT, wbf+28672, b_bwd+64,
                                                 gates, 2, accb, nullptr,
                                                 nullptr, nullptr, nullptr, nullptr, nullptr);
    k_diffmm<true ,false><<<3072,256,0,stream>>>(aadp_bf, xTp,  wbf+32768, b_adp,
                                                 gates, 3, accb, tmpT,
                                                 nullptr, nullptr, nullptr, nullptr, nullptr);
    k_diffmm<false,true ><<<3072,256,0,stream>>>(aadp_bf, tmpT, wbf+36864, b_adp+64,
                                                 gates, 3, accb, nullptr,
                                                 x, scaleb, gamma, beta, out);
}